// Round 4
// baseline (1618.137 us; speedup 1.0000x reference)
//
#include <hip/hip_runtime.h>
#include <hip/hip_bf16.h>

typedef __attribute__((ext_vector_type(8))) short short8;
typedef __attribute__((ext_vector_type(4))) float f32x4;

#define B_ 512
#define T_ 256
#define GT (B_ * T_)
#define NN 4800
#define NC 240
#define CL 20
#define KLEN 600

__device__ __forceinline__ short bf16rne(float x) {
    unsigned u = __float_as_uint(x);
    u = (u + 0x7FFFu + ((u >> 16) & 1u)) >> 16;
    return (short)u;
}
// monotonic float->uint key (ascending float == ascending uint)
__device__ __forceinline__ unsigned fkey(float f) {
    unsigned i = __float_as_uint(f);
    return (i & 0x80000000u) ? ~i : (i | 0x80000000u);
}

// device-wide barrier: all B_ blocks co-resident (guaranteed by __launch_bounds__(256,2):
// <=256 VGPR -> >=2 blocks/CU -> capacity 512 >= grid 512). Counters zeroed by the
// pre-kernel hipMemsetAsync each call.
__device__ __forceinline__ void gsync(unsigned* bars, int id) {
    __syncthreads();
    if (threadIdx.x == 0) {
        __threadfence();
        __hip_atomic_fetch_add(&bars[id], 1u, __ATOMIC_ACQ_REL, __HIP_MEMORY_SCOPE_AGENT);
        while (__hip_atomic_load(&bars[id], __ATOMIC_ACQUIRE, __HIP_MEMORY_SCOPE_AGENT) < (unsigned)B_)
            __builtin_amdgcn_s_sleep(2);
    }
    __syncthreads();
}

// ---- rank counting (brute force, 64-bit keys) + exp tables ----
__device__ void krank_f(const float* __restrict__ s, const float* __restrict__ t,
                        int* __restrict__ rk, float* __restrict__ e1, float* __restrict__ e2) {
    __shared__ unsigned long long ts64[KLEN];
    for (int task = blockIdx.x; task < 969; task += B_) {
        __syncthreads();
        if (task < 912) {
            int kc = task / 114, rem = task % 114, h = rem / 38, qb = rem % 38;
            const float* tp = t + h * NN + kc * KLEN;
            for (int k = threadIdx.x; k < KLEN; k += T_)
                ts64[k] = ((unsigned long long)fkey(tp[k]) << 13) | (unsigned long long)(kc * KLEN + k);
            __syncthreads();
            int q = qb * T_ + threadIdx.x;
            if (q < 2 * NN) {
                unsigned long long u = (q < NN)
                    ? ((unsigned long long)fkey(t[h * NN + q]) << 13) | (unsigned long long)q
                    : ((unsigned long long)fkey(-s[h * NN + q - NN]) << 13) | 8191ULL;
                int cnt = 0;
#pragma unroll 8
                for (int k = 0; k < KLEN; ++k) cnt += (ts64[k] < u) ? 1 : 0;
                atomicAdd(&rk[h * 2 * NN + q], cnt);
            }
        } else {
            int base = (task - 912) * T_ + threadIdx.x;
            if (base < 3 * NN) {
                float tv = t[base];
                e1[base] = __expf(tv);
                e2[base] = __expf(0.2f * tv);
            }
        }
    }
}

// ---- chunk totals (gather via inv) ----
template <int Dc, int HD, int Dd, int PACK>
__device__ void phA_f(const float* __restrict__ hsrc, const int* __restrict__ inv,
                      const float* __restrict__ e1, const float* __restrict__ e2,
                      float* __restrict__ T1, float* __restrict__ T2) {
    constexpr int PER = NC / PACK;
    int sub = threadIdx.x / Dc;
    int d = threadIdx.x - sub * Dc;
    for (int task = blockIdx.x; task < 3 * PER; task += B_) {
        if (sub < PACK) {
            int h = task / PER, ct = task % PER;
            int c = ct * PACK + sub;
            float a1 = 0.f, a2 = 0.f;
#pragma unroll
            for (int p = 0; p < CL; ++p) {
                int j = inv[h * NN + c * CL + p];
                float hv = (d < Dd) ? hsrc[(size_t)j * HD + h * Dd + d] : 1.f;
                a1 += e1[h * NN + j] * hv;
                a2 += e2[h * NN + j] * hv;
            }
            T1[(h * NC + c) * Dc + d] = a1;
            T2[(h * NC + c) * Dc + d] = a2;
        }
    }
}

// ---- scan chunk totals -> offsets (fp64 accumulator) ----
template <int Dc>
__device__ void phB_f(const float* __restrict__ T1, const float* __restrict__ T2,
                      float* __restrict__ O1, float* __restrict__ O2) {
    int g = blockIdx.x * T_ + threadIdx.x;
    if (g < 2 * 3 * Dc) {
        int dir = g / (3 * Dc), rest = g % (3 * Dc), h = rest / Dc, d = rest % Dc;
        if (dir == 0) {
            double r = 0; O1[(h * NC + NC - 1) * Dc + d] = 0.f;
#pragma unroll 8
            for (int c = NC - 2; c >= 0; --c) { r += (double)T1[(h * NC + c + 1) * Dc + d]; O1[(h * NC + c) * Dc + d] = (float)r; }
        } else {
            double r = 0; O2[h * NC * Dc + d] = 0.f;
#pragma unroll 8
            for (int c = 1; c < NC; ++c) { r += (double)T2[(h * NC + c - 1) * Dc + d]; O2[(h * NC + c) * Dc + d] = (float)r; }
        }
    }
}

// ---- emit full prefix (exclusive, e2) / suffix (inclusive, e1) arrays ----
template <int Dc, int HD, int Dd, int PACK>
__device__ void phC_f(const float* __restrict__ hsrc, const int* __restrict__ inv,
                      const float* __restrict__ e1, const float* __restrict__ e2,
                      const float* __restrict__ O1, const float* __restrict__ O2,
                      float* __restrict__ Suf1, float* __restrict__ Pre2) {
    constexpr int PER = NC / PACK;
    int sub = threadIdx.x / Dc;
    int d = threadIdx.x - sub * Dc;
    for (int task = blockIdx.x; task < 3 * PER; task += B_) {
        if (sub < PACK) {
            int h = task / PER, ct = task % PER;
            int c = ct * PACK + sub;
            float hv[CL], w1[CL], w2[CL];
#pragma unroll
            for (int p = 0; p < CL; ++p) {
                int j = inv[h * NN + c * CL + p];
                hv[p] = (d < Dd) ? hsrc[(size_t)j * HD + h * Dd + d] : 1.f;
                w1[p] = e1[h * NN + j];
                w2[p] = e2[h * NN + j];
            }
            float r2 = O2[(h * NC + c) * Dc + d];
#pragma unroll
            for (int p = 0; p < CL; ++p) {
                int pp = c * CL + p;
                Pre2[((size_t)h * (NN + 1) + pp) * Dc + d] = r2;
                r2 += w2[p] * hv[p];
            }
            if (c == NC - 1) {
                Pre2[((size_t)h * (NN + 1) + NN) * Dc + d] = r2;
                Suf1[((size_t)h * (NN + 1) + NN) * Dc + d] = 0.f;
            }
            float r1 = O1[(h * NC + c) * Dc + d];
#pragma unroll
            for (int p = CL - 1; p >= 0; --p) {
                int pp = c * CL + p;
                r1 += w1[p] * hv[p];
                Suf1[((size_t)h * (NN + 1) + pp) * Dc + d] = r1;
            }
        }
    }
}

// ---- bf16 MFMA GEMM tiles: C[M,N] = A[M,K] @ BT[N,K]^T ----
template <int K, int NTI, bool RELU, bool OBF>
__device__ void gemm_f(const short* __restrict__ A, const short* __restrict__ BT,
                       const float* __restrict__ bias, float* __restrict__ Cf, short* __restrict__ Cb) {
    const int tid = threadIdx.x, lane = tid & 63, w = tid >> 6, q = lane >> 4, mr = lane & 15;
    constexpr int N = NTI * 64;
    for (int task = blockIdx.x; task < 75 * NTI; task += B_) {
        int mb = task % 75, nb = task / 75;
        int m = mb * 64 + w * 16 + mr, n0 = nb * 64;
        f32x4 acc[4];
#pragma unroll
        for (int n = 0; n < 4; ++n) acc[n] = (f32x4){0.f, 0.f, 0.f, 0.f};
#pragma unroll
        for (int k0 = 0; k0 < K; k0 += 32) {
            short8 af = *(const short8*)(A + (size_t)m * K + k0 + q * 8);
#pragma unroll
            for (int n = 0; n < 4; ++n) {
                short8 bf = *(const short8*)(BT + (size_t)(n0 + n * 16 + mr) * K + k0 + q * 8);
                acc[n] = __builtin_amdgcn_mfma_f32_16x16x32_bf16(af, bf, acc[n], 0, 0, 0);
            }
        }
#pragma unroll
        for (int n = 0; n < 4; ++n) {
            int col = n0 + n * 16 + mr;
            float bv = bias ? bias[col] : 0.f;
#pragma unroll
            for (int r = 0; r < 4; ++r) {
                int row = mb * 64 + w * 16 + q * 4 + r;
                float v = acc[n][r] + bv;
                if (RELU) v = fmaxf(v, 0.f);
                if (OBF) Cb[(size_t)row * N + col] = bf16rne(v);
                else     Cf[(size_t)row * N + col] = v;
            }
        }
    }
}

extern "C" __global__ __launch_bounds__(T_, 2) void mega(
    char* __restrict__ ws,
    const float* __restrict__ flat, const float* __restrict__ amask,
    const float* __restrict__ W1, const float* __restrict__ as1, const float* __restrict__ ad1,
    const float* __restrict__ W2, const float* __restrict__ as2, const float* __restrict__ ad2,
    const float* __restrict__ P1, const float* __restrict__ b1,
    const float* __restrict__ P2, const float* __restrict__ b2,
    float* __restrict__ out) {
    // -------- workspace map (byte offsets; region [0,230528) zeroed by memset) --------
    unsigned* bars = (unsigned*)(ws + 0);            // 128 B
    int*    rk1   = (int*)  (ws + 128);              // 3*9600*4
    int*    rk2   = (int*)  (ws + 115328);
    float*  h1    = (float*)(ws + 230528);           // 4800*192
    float*  s1    = (float*)(ws + 3916928);
    float*  t1    = (float*)(ws + 3974528);
    float*  s2    = (float*)(ws + 4032128);
    float*  t2    = (float*)(ws + 4089728);
    float*  e1    = (float*)(ws + 4147328);
    float*  e2    = (float*)(ws + 4204928);
    int*    inv   = (int*)  (ws + 4262528);
    float*  Tot1  = (float*)(ws + 4320128);          // 3*240*129 (layer1 uses stride 65)
    float*  Tot2  = (float*)(ws + 4691648);
    float*  Off1  = (float*)(ws + 5063168);
    float*  Off2  = (float*)(ws + 5434688);
    float*  Suf1  = (float*)(ws + 5806208);          // 3*4801*129 f
    float*  Pre2  = (float*)(ws + 13238160);
    short*  h1abf = (short*)(ws + 20670112);         // 4800*192 bf16
    float*  h2    = (float*)(ws + 22513312);         // 4800*384 f32
    short*  gbf   = (short*)(ws + 29886112);         // 4800*160 bf16
    short*  f1bf  = (short*)(ws + 31422112);         // 4800*128 bf16
    float*  f2    = (float*)(ws + 32650912);         // 4800*64 f32
    short*  W2T   = (short*)(ws + 33879712);         // 384*192 bf16
    short*  P1T   = (short*)(ws + 34027168);         // 128*160 bf16
    short*  P2T   = (short*)(ws + 34068128);         // 64*128 bf16

    const int tid = threadIdx.x, bid = blockIdx.x;
    const int gtid = bid * T_ + tid;
    const int lane = tid & 63;
    const int gw = bid * 4 + (tid >> 6);

    // ---- P1: h1 elementwise + weight transposes + s1/t1 wave dots ----
    for (int x = gtid; x < 921600 + 102400; x += GT) {
        if (x < 921600) {
            int i = x / 192, c = x % 192;
            const float* fr = flat + i * 15;
            float acc = 0.f;
#pragma unroll
            for (int f = 0; f < 15; ++f) acc += fr[f] * W1[f * 192 + c];
            h1[x] = acc;
        } else {
            int y = x - 921600;
            if (y < 73728)      { int n = y / 192, k = y % 192; W2T[y] = bf16rne(W2[k * 384 + n]); }
            else if (y < 94208) { int z = y - 73728; int n = z / 160, k = z % 160; P1T[z] = bf16rne(k < 143 ? P1[k * 128 + n] : 0.f); }
            else                { int z = y - 94208; int n = z / 128, k = z % 128; P2T[z] = bf16rne(P2[k * 64 + n]); }
        }
    }
    for (int task = gw; task < 3 * NN; task += B_ * 4) {   // s1/t1 (recompute hv; no intra-phase dep)
        int h = task / NN, i = task % NN;
        int col = h * 64 + lane;
        const float* fr = flat + i * 15;
        float hv = 0.f;
#pragma unroll
        for (int f = 0; f < 15; ++f) hv += fr[f] * W1[f * 192 + col];
        float ps = hv * as1[col], pt = hv * ad1[col];
#pragma unroll
        for (int off = 32; off; off >>= 1) { ps += __shfl_xor(ps, off); pt += __shfl_xor(pt, off); }
        if (lane == 0) { s1[h * NN + i] = ps; t1[h * NN + i] = pt; }
    }
    gsync(bars, 0);

    // ---- layer 1 attention ----
    krank_f(s1, t1, rk1, e1, e2);
    gsync(bars, 1);
    for (int x = gtid; x < 3 * NN; x += GT) { int h = x / NN, q = x % NN; inv[h * NN + rk1[h * 2 * NN + q]] = q; }
    gsync(bars, 2);
    phA_f<65, 192, 64, 3>(h1, inv, e1, e2, Tot1, Tot2);
    gsync(bars, 3);
    phB_f<65>(Tot1, Tot2, Off1, Off2);
    gsync(bars, 4);
    phC_f<65, 192, 64, 3>(h1, inv, e1, e2, Off1, Off2, Suf1, Pre2);
    gsync(bars, 5);
    for (int x = gtid; x < NN * 192; x += GT) {            // kout1: combine + ELU -> h1abf
        int i = x / 192, cc = x % 192, h = cc >> 6, d = cc & 63;
        float sv = s1[h * NN + i];
        float a = __expf(sv), b = __expf(0.2f * sv);
        int r = rk1[h * 2 * NN + NN + i];
        size_t base = ((size_t)h * (NN + 1) + r) * 65;
        float num = a * Suf1[base + d] + b * Pre2[base + d];
        float den = a * Suf1[base + 64] + b * Pre2[base + 64];
        float v = num / den;
        v = v > 0.f ? v : (__expf(v) - 1.f);
        h1abf[x] = bf16rne(v);
    }
    gsync(bars, 6);
    gemm_f<192, 6, false, false>(h1abf, W2T, nullptr, h2, nullptr);
    gsync(bars, 7);
    for (int task = gw; task < 3 * NN; task += B_ * 4) {   // s2/t2 wave dots
        int h = task / NN, i = task % NN;
        const float* hp = h2 + (size_t)i * 384 + h * 128;
        float v0 = hp[lane], v1 = hp[lane + 64];
        float ps = v0 * as2[h * 128 + lane] + v1 * as2[h * 128 + 64 + lane];
        float pt = v0 * ad2[h * 128 + lane] + v1 * ad2[h * 128 + 64 + lane];
#pragma unroll
        for (int off = 32; off; off >>= 1) { ps += __shfl_xor(ps, off); pt += __shfl_xor(pt, off); }
        if (lane == 0) { s2[h * NN + i] = ps; t2[h * NN + i] = pt; }
    }
    gsync(bars, 8);

    // ---- layer 2 attention ----
    krank_f(s2, t2, rk2, e1, e2);
    gsync(bars, 9);
    for (int x = gtid; x < 3 * NN; x += GT) { int h = x / NN, q = x % NN; inv[h * NN + rk2[h * 2 * NN + q]] = q; }
    gsync(bars, 10);
    phA_f<129, 384, 128, 1>(h2, inv, e1, e2, Tot1, Tot2);
    gsync(bars, 11);
    phB_f<129>(Tot1, Tot2, Off1, Off2);
    gsync(bars, 12);
    phC_f<129, 384, 128, 1>(h2, inv, e1, e2, Off1, Off2, Suf1, Pre2);
    gsync(bars, 13);
    for (int x = gtid; x < NN * 160; x += GT) {            // kout2: head-mean + concat -> gbf
        int i = x / 160, c = x % 160;
        float v;
        if (c < 128) {
            float acc = 0.f;
#pragma unroll
            for (int h = 0; h < 3; ++h) {
                float sv = s2[h * NN + i];
                float a = __expf(sv), b = __expf(0.2f * sv);
                int r = rk2[h * 2 * NN + NN + i];
                size_t base = ((size_t)h * (NN + 1) + r) * 129;
                float num = a * Suf1[base + c] + b * Pre2[base + c];
                float den = a * Suf1[base + 128] + b * Pre2[base + 128];
                acc += num / den;
            }
            v = acc * (1.f / 3.f);
        } else if (c < 143) v = flat[i * 15 + (c - 128)];
        else v = 0.f;
        gbf[x] = bf16rne(v);
    }
    gsync(bars, 14);
    gemm_f<160, 2, true, true>(gbf, P1T, b1, nullptr, f1bf);
    gsync(bars, 15);
    gemm_f<128, 1, true, false>(f1bf, P2T, b2, f2, nullptr);
    gsync(bars, 16);
    for (int x = gtid; x < 2048 + 4832; x += GT) {         // mean pool + mask passthrough
        if (x < 2048) {
            int b = x >> 6, d = x & 63;
            float acc = 0.f;
#pragma unroll 10
            for (int j = 0; j < 150; ++j) acc += f2[(size_t)(b * 150 + j) * 64 + d];
            out[x] = acc * (1.f / 150.f);
        } else {
            out[x] = amask[x - 2048];
        }
    }
}

extern "C" void kernel_launch(void* const* d_in, const int* in_sizes, int n_in,
                              void* d_out, int out_size, void* d_ws, size_t ws_size,
                              hipStream_t stream) {
    const float* flat   = (const float*)d_in[0];
    const float* amask  = (const float*)d_in[1];
    const float* W1     = (const float*)d_in[2];
    const float* a_src1 = (const float*)d_in[3];
    const float* a_dst1 = (const float*)d_in[4];
    const float* W2     = (const float*)d_in[5];
    const float* a_src2 = (const float*)d_in[6];
    const float* a_dst2 = (const float*)d_in[7];
    const float* P1     = (const float*)d_in[8];
    const float* b1     = (const float*)d_in[9];
    const float* P2     = (const float*)d_in[10];
    const float* b2     = (const float*)d_in[11];

    // zero barrier counters + rank accumulators (230528 B)
    hipMemsetAsync(d_ws, 0, 230528, stream);
    mega<<<B_, T_, 0, stream>>>((char*)d_ws, flat, amask, W1, a_src1, a_dst1,
                                W2, a_src2, a_dst2, P1, b1, P2, b2, (float*)d_out);
}

// Round 5
// 343.546 us; speedup vs baseline: 4.7101x; 4.7101x over previous
//
#include <hip/hip_runtime.h>
#include <hip/hip_bf16.h>

typedef __attribute__((ext_vector_type(8))) short short8;
typedef __attribute__((ext_vector_type(4))) float f32x4;

#define NN 4800
#define NC 240
#define CL 20
#define KLEN 600

__device__ __forceinline__ short bf16rne(float x) {
    unsigned u = __float_as_uint(x);
    u = (u + 0x7FFFu + ((u >> 16) & 1u)) >> 16;
    return (short)u;
}
// monotonic float->uint key (ascending float == ascending uint)
__device__ __forceinline__ unsigned fkey(float f) {
    unsigned i = __float_as_uint(f);
    return (i & 0x80000000u) ? ~i : (i | 0x80000000u);
}

// ---------- prep: h1, weight transposes, s1/t1 dots, mask copy ----------
__global__ __launch_bounds__(256) void prep(
    const float* __restrict__ flat, const float* __restrict__ amask,
    const float* __restrict__ W1, const float* __restrict__ as1, const float* __restrict__ ad1,
    const float* __restrict__ W2, const float* __restrict__ P1, const float* __restrict__ P2,
    float* __restrict__ h1, float* __restrict__ s1, float* __restrict__ t1,
    short* __restrict__ W2T, short* __restrict__ P1T, short* __restrict__ P2T,
    float* __restrict__ out) {
    const int gtid = blockIdx.x * 256 + threadIdx.x;
    const int GT = 1200 * 256;
    for (int x = gtid; x < 1028832; x += GT) {
        if (x < 921600) {
            int i = x / 192, c = x % 192;
            const float* fr = flat + i * 15;
            float acc = 0.f;
#pragma unroll
            for (int f = 0; f < 15; ++f) acc += fr[f] * W1[f * 192 + c];
            h1[x] = acc;
        } else if (x < 995328) {
            int y = x - 921600; int n = y / 192, k = y % 192;
            W2T[y] = bf16rne(W2[k * 384 + n]);
        } else if (x < 1015808) {
            int z = x - 995328; int n = z / 160, k = z % 160;
            P1T[z] = bf16rne(k < 143 ? P1[k * 128 + n] : 0.f);
        } else if (x < 1024000) {
            int z = x - 1015808; int n = z / 128, k = z % 128;
            P2T[z] = bf16rne(P2[k * 64 + n]);
        } else {
            int m = x - 1024000;              // mask passthrough (4832)
            out[2048 + m] = amask[m];
        }
    }
    const int lane = threadIdx.x & 63;
    const int gw = (gtid >> 6);
    for (int task = gw; task < 3 * NN; task += (GT >> 6)) {
        int h = task / NN, i = task % NN;
        int col = h * 64 + lane;
        const float* fr = flat + i * 15;
        float hv = 0.f;
#pragma unroll
        for (int f = 0; f < 15; ++f) hv += fr[f] * W1[f * 192 + col];
        float ps = hv * as1[col], pt = hv * ad1[col];
#pragma unroll
        for (int off = 32; off; off >>= 1) { ps += __shfl_xor(ps, off); pt += __shfl_xor(pt, off); }
        if (lane == 0) { s1[h * NN + i] = ps; t1[h * NN + i] = pt; }
    }
}

// ---------- krank: rank counting via atomics. grid (38,3,8) ----------
// rk[h][q<NN]  = rank of t_q (strict total order via 64-bit key w/ index tiebreak)
// rk[h][NN+i]  = #{j : t_j <= -s_i}
__global__ __launch_bounds__(256) void krank(const float* __restrict__ s, const float* __restrict__ t,
                                             int* __restrict__ rk) {
    __shared__ unsigned long long ts64[KLEN];
    const int h = blockIdx.y, kc = blockIdx.z;
    const float* tp = t + h * NN + kc * KLEN;
    for (int k = threadIdx.x; k < KLEN; k += 256)
        ts64[k] = ((unsigned long long)fkey(tp[k]) << 13) | (unsigned long long)(kc * KLEN + k);
    __syncthreads();
    int q = blockIdx.x * 256 + threadIdx.x;
    if (q >= 2 * NN) return;
    unsigned long long u = (q < NN)
        ? ((unsigned long long)fkey(t[h * NN + q]) << 13) | (unsigned long long)q
        : ((unsigned long long)fkey(-s[h * NN + q - NN]) << 13) | 8191ULL;
    int cnt = 0;
#pragma unroll 8
    for (int k = 0; k < KLEN; ++k) cnt += (ts64[k] < u) ? 1 : 0;
    atomicAdd(&rk[h * 2 * NN + q], cnt);
}

// ---------- phA: chunk totals; local inv rebuilt from rk. grid (NC/PACK, 3) ----------
template <int Dc, int HD, int Dd, int PACK>
__global__ __launch_bounds__(256) void phA(const float* __restrict__ hsrc, const int* __restrict__ rk,
                                           const float* __restrict__ t,
                                           float* __restrict__ T1, float* __restrict__ T2) {
    __shared__ int inv_l[PACK * CL];
    __shared__ float w1s[PACK * CL], w2s[PACK * CL];
    const int h = blockIdx.y, tid = threadIdx.x;
    const int base = blockIdx.x * (PACK * CL);
    for (int j = tid; j < NN; j += 256) {
        unsigned rr = (unsigned)(rk[h * 2 * NN + j] - base);
        if (rr < PACK * CL) inv_l[rr] = j;
    }
    __syncthreads();
    if (tid < PACK * CL) {
        float tv = t[h * NN + inv_l[tid]];
        w1s[tid] = __expf(tv); w2s[tid] = __expf(0.2f * tv);
    }
    __syncthreads();
    int sub = tid / Dc, d = tid - sub * Dc;
    if (sub < PACK) {
        int c = blockIdx.x * PACK + sub;
        float a1 = 0.f, a2 = 0.f;
#pragma unroll
        for (int p = 0; p < CL; ++p) {
            int j = inv_l[sub * CL + p];
            float hv = (d < Dd) ? hsrc[(size_t)j * HD + h * Dd + d] : 1.f;
            a1 += w1s[sub * CL + p] * hv;
            a2 += w2s[sub * CL + p] * hv;
        }
        T1[(h * NC + c) * Dc + d] = a1;
        T2[(h * NC + c) * Dc + d] = a2;
    }
}

// ---------- phC: per-chunk offset (sums all Tot, fp64) + emit Suf1/Pre2 ----------
template <int Dc, int HD, int Dd, int PACK>
__global__ __launch_bounds__(256) void phC(const float* __restrict__ hsrc, const int* __restrict__ rk,
                                           const float* __restrict__ t,
                                           const float* __restrict__ T1, const float* __restrict__ T2,
                                           float* __restrict__ Suf1, float* __restrict__ Pre2) {
    __shared__ int inv_l[PACK * CL];
    __shared__ float w1s[PACK * CL], w2s[PACK * CL];
    const int h = blockIdx.y, tid = threadIdx.x;
    const int base = blockIdx.x * (PACK * CL);
    for (int j = tid; j < NN; j += 256) {
        unsigned rr = (unsigned)(rk[h * 2 * NN + j] - base);
        if (rr < PACK * CL) inv_l[rr] = j;
    }
    __syncthreads();
    if (tid < PACK * CL) {
        float tv = t[h * NN + inv_l[tid]];
        w1s[tid] = __expf(tv); w2s[tid] = __expf(0.2f * tv);
    }
    __syncthreads();
    int sub = tid / Dc, d = tid - sub * Dc;
    if (sub < PACK) {
        int c = blockIdx.x * PACK + sub;
        double o2 = 0.0, o1 = 0.0;
        for (int cp = 0; cp < c; ++cp)       o2 += (double)T2[(h * NC + cp) * Dc + d];
        for (int cp = c + 1; cp < NC; ++cp)  o1 += (double)T1[(h * NC + cp) * Dc + d];
        float hv[CL];
#pragma unroll
        for (int p = 0; p < CL; ++p) {
            int j = inv_l[sub * CL + p];
            hv[p] = (d < Dd) ? hsrc[(size_t)j * HD + h * Dd + d] : 1.f;
        }
        float r2 = (float)o2;
#pragma unroll
        for (int p = 0; p < CL; ++p) {
            int pp = c * CL + p;
            Pre2[((size_t)(h * (NN + 1)) + pp) * Dc + d] = r2;
            r2 += w2s[sub * CL + p] * hv[p];
        }
        if (c == NC - 1) {
            Pre2[((size_t)(h * (NN + 1)) + NN) * Dc + d] = r2;
            Suf1[((size_t)(h * (NN + 1)) + NN) * Dc + d] = 0.f;
        }
        float r1 = (float)o1;
#pragma unroll
        for (int p = CL - 1; p >= 0; --p) {
            int pp = c * CL + p;
            r1 += w1s[sub * CL + p] * hv[p];
            Suf1[((size_t)(h * (NN + 1)) + pp) * Dc + d] = r1;
        }
    }
}

// ---------- TAIL1: kout1 (LDS A-tile) + gemm h2 + fused s2/t2 dots. grid (75,6) ----------
__global__ __launch_bounds__(256) void tail1(
    const float* __restrict__ s1, const int* __restrict__ rk1,
    const float* __restrict__ Suf1, const float* __restrict__ Pre2,
    const short* __restrict__ W2T, const float* __restrict__ as2, const float* __restrict__ ad2,
    float* __restrict__ h2, float* __restrict__ s2, float* __restrict__ t2) {
    __shared__ short At[64][200];
    const int mb = blockIdx.x, nb = blockIdx.y, tid = threadIdx.x;
    for (int e = tid; e < 64 * 192; e += 256) {   // kout1 for this row-tile
        int row = e / 192, cc = e % 192;
        int i = mb * 64 + row;
        int h = cc >> 6, d = cc & 63;
        float sv = s1[h * NN + i];
        float a = __expf(sv), b = __expf(0.2f * sv);
        int r = rk1[h * 2 * NN + NN + i];
        size_t basep = ((size_t)(h * (NN + 1) + r)) * 65;
        float num = a * Suf1[basep + d] + b * Pre2[basep + d];
        float den = a * Suf1[basep + 64] + b * Pre2[basep + 64];
        float v = num / den;
        v = v > 0.f ? v : (__expf(v) - 1.f);      // ELU
        At[row][cc] = bf16rne(v);
    }
    __syncthreads();
    const int lane = tid & 63, w = tid >> 6, q = lane >> 4, mr = lane & 15;
    const int n0 = nb * 64;
    f32x4 acc[4];
#pragma unroll
    for (int n = 0; n < 4; ++n) acc[n] = (f32x4){0.f, 0.f, 0.f, 0.f};
#pragma unroll
    for (int k0 = 0; k0 < 192; k0 += 32) {
        short8 af = *(const short8*)&At[w * 16 + mr][k0 + q * 8];
#pragma unroll
        for (int n = 0; n < 4; ++n) {
            short8 bf = *(const short8*)(W2T + (size_t)(n0 + n * 16 + mr) * 192 + k0 + q * 8);
            acc[n] = __builtin_amdgcn_mfma_f32_16x16x32_bf16(af, bf, acc[n], 0, 0, 0);
        }
    }
    const int hh = nb >> 1;
    float pse[4] = {0.f, 0.f, 0.f, 0.f}, pte[4] = {0.f, 0.f, 0.f, 0.f};
#pragma unroll
    for (int n = 0; n < 4; ++n) {
        int col = n0 + n * 16 + mr;
        float va = as2[col - hh * 128 + hh * 128];  // as2[h*128 + c], col already h*128+c
        float vd = ad2[col];
        va = as2[col];
#pragma unroll
        for (int r = 0; r < 4; ++r) {
            int row = mb * 64 + w * 16 + q * 4 + r;
            float v = acc[n][r];
            h2[(size_t)row * 384 + col] = v;
            pse[r] += v * va;
            pte[r] += v * vd;
        }
    }
#pragma unroll
    for (int off = 1; off < 16; off <<= 1) {
#pragma unroll
        for (int r = 0; r < 4; ++r) {
            pse[r] += __shfl_xor(pse[r], off);
            pte[r] += __shfl_xor(pte[r], off);
        }
    }
    if (mr == 0) {
#pragma unroll
        for (int r = 0; r < 4; ++r) {
            int row = mb * 64 + w * 16 + q * 4 + r;
            atomicAdd(&s2[hh * NN + row], pse[r]);
            atomicAdd(&t2[hh * NN + row], pte[r]);
        }
    }
}

// ---------- TAIL2: kout2 (g tile) + F1 + F2 + mean pool. grid 75 ----------
__global__ __launch_bounds__(256) void tail2(
    const float* __restrict__ s2, const int* __restrict__ rk2,
    const float* __restrict__ Suf1, const float* __restrict__ Pre2,
    const float* __restrict__ flat, const short* __restrict__ P1T, const short* __restrict__ P2T,
    const float* __restrict__ b1, const float* __restrict__ b2,
    float* __restrict__ out) {
    __shared__ short g[64][168];
    __shared__ short f1[64][136];
    const int mb = blockIdx.x, tid = threadIdx.x;
    for (int e = tid; e < 64 * 160; e += 256) {   // build g tile
        int row = e / 160, c = e % 160;
        int i = mb * 64 + row;
        float v;
        if (c < 128) {
            float acc = 0.f;
#pragma unroll
            for (int h = 0; h < 3; ++h) {
                float sv = s2[h * NN + i];
                float a = __expf(sv), b = __expf(0.2f * sv);
                int r = rk2[h * 2 * NN + NN + i];
                size_t basep = ((size_t)(h * (NN + 1) + r)) * 129;
                float num = a * Suf1[basep + c] + b * Pre2[basep + c];
                float den = a * Suf1[basep + 128] + b * Pre2[basep + 128];
                acc += num / den;
            }
            v = acc * (1.f / 3.f);
        } else if (c < 143) v = flat[i * 15 + (c - 128)];
        else v = 0.f;
        g[row][c] = bf16rne(v);
    }
    __syncthreads();
    const int lane = tid & 63, w = tid >> 6, q = lane >> 4, mr = lane & 15;
    // F1: [64 rows] x 128 cols, K=160
    f32x4 a1[8];
#pragma unroll
    for (int n = 0; n < 8; ++n) a1[n] = (f32x4){0.f, 0.f, 0.f, 0.f};
#pragma unroll
    for (int k0 = 0; k0 < 160; k0 += 32) {
        short8 af = *(const short8*)&g[w * 16 + mr][k0 + q * 8];
#pragma unroll
        for (int n = 0; n < 8; ++n) {
            short8 bf = *(const short8*)(P1T + (size_t)(n * 16 + mr) * 160 + k0 + q * 8);
            a1[n] = __builtin_amdgcn_mfma_f32_16x16x32_bf16(af, bf, a1[n], 0, 0, 0);
        }
    }
#pragma unroll
    for (int n = 0; n < 8; ++n) {
        int col = n * 16 + mr;
        float bv = b1[col];
#pragma unroll
        for (int r = 0; r < 4; ++r) {
            int row = w * 16 + q * 4 + r;
            f1[row][col] = bf16rne(fmaxf(a1[n][r] + bv, 0.f));
        }
    }
    __syncthreads();
    // F2: [64 rows] x 64 cols, K=128
    f32x4 a2[4];
#pragma unroll
    for (int n = 0; n < 4; ++n) a2[n] = (f32x4){0.f, 0.f, 0.f, 0.f};
#pragma unroll
    for (int k0 = 0; k0 < 128; k0 += 32) {
        short8 af = *(const short8*)&f1[w * 16 + mr][k0 + q * 8];
#pragma unroll
        for (int n = 0; n < 4; ++n) {
            short8 bf = *(const short8*)(P2T + (size_t)(n * 16 + mr) * 128 + k0 + q * 8);
            a2[n] = __builtin_amdgcn_mfma_f32_16x16x32_bf16(af, bf, a2[n], 0, 0, 0);
        }
    }
    float* f2f = (float*)&g[0][0];                 // reuse g region: 64*65 f32 = 16.6 KB <= 21.5 KB
#pragma unroll
    for (int n = 0; n < 4; ++n) {
        int col = n * 16 + mr;
        float bv = b2[col];
#pragma unroll
        for (int r = 0; r < 4; ++r) {
            int row = w * 16 + q * 4 + r;
            f2f[row * 65 + col] = fmaxf(a2[n][r] + bv, 0.f);
        }
    }
    __syncthreads();
    if (tid < 64) {                                // mean pool over jobs (atomics into zeroed out)
        int d = tid;
        int b0 = (mb * 64) / 150;
        int bend = (mb * 64 + 63) / 150;
        float sa = 0.f, sb = 0.f;
        for (int row = 0; row < 64; ++row) {
            float v = f2f[row * 65 + d];
            int b = (mb * 64 + row) / 150;
            if (b == b0) sa += v; else sb += v;
        }
        atomicAdd(&out[b0 * 64 + d], sa * (1.f / 150.f));
        if (bend != b0) atomicAdd(&out[bend * 64 + d], sb * (1.f / 150.f));
    }
}

extern "C" void kernel_launch(void* const* d_in, const int* in_sizes, int n_in,
                              void* d_out, int out_size, void* d_ws, size_t ws_size,
                              hipStream_t stream) {
    const float* flat   = (const float*)d_in[0];
    const float* amask  = (const float*)d_in[1];
    const float* W1     = (const float*)d_in[2];
    const float* a_src1 = (const float*)d_in[3];
    const float* a_dst1 = (const float*)d_in[4];
    const float* W2     = (const float*)d_in[5];
    const float* a_src2 = (const float*)d_in[6];
    const float* a_dst2 = (const float*)d_in[7];
    const float* P1     = (const float*)d_in[8];
    const float* b1     = (const float*)d_in[9];
    const float* P2     = (const float*)d_in[10];
    const float* b2     = (const float*)d_in[11];
    float* out = (float*)d_out;

    char* wsb = (char*)d_ws;
    // byte offsets; region [0, 345600) zeroed every call (rk1, rk2, s2, t2)
    int*   rk1  = (int*)  (wsb + 0);          // 3*9600*4 = 115200
    int*   rk2  = (int*)  (wsb + 115200);     // 115200
    float* s2   = (float*)(wsb + 230400);     // 57600
    float* t2   = (float*)(wsb + 288000);     // 57600  -> memset end 345600
    float* s1   = (float*)(wsb + 345600);     // 57600
    float* t1   = (float*)(wsb + 403200);     // 57600
    float* h1   = (float*)(wsb + 460800);     // 4800*192*4 = 3686400
    float* Tot1 = (float*)(wsb + 4147200);    // 3*240*129*4 = 371520
    float* Tot2 = (float*)(wsb + 4518720);    // 371520
    float* Suf1 = (float*)(wsb + 4890240);    // 3*4801*129*4 = 7431948 -> pad 7431952
    float* Pre2 = (float*)(wsb + 12322192);   // 7431952
    float* h2   = (float*)(wsb + 19754144);   // 4800*384*4 = 7372800
    short* W2T  = (short*)(wsb + 27126944);   // 147456
    short* P1T  = (short*)(wsb + 27274400);   // 40960
    short* P2T  = (short*)(wsb + 27315360);   // 16384 -> total 27331744 B

    hipMemsetAsync(d_ws, 0, 345600, stream);
    hipMemsetAsync(d_out, 0, 2048 * 4, stream);   // pool accumulators

    prep<<<1200, 256, 0, stream>>>(flat, amask, W1, a_src1, a_dst1, W2, P1, P2,
                                   h1, s1, t1, W2T, P1T, P2T, out);
    // layer 1
    krank<<<dim3(38, 3, 8), 256, 0, stream>>>(s1, t1, rk1);
    phA<65, 192, 64, 3><<<dim3(80, 3), 256, 0, stream>>>(h1, rk1, t1, Tot1, Tot2);
    phC<65, 192, 64, 3><<<dim3(80, 3), 256, 0, stream>>>(h1, rk1, t1, Tot1, Tot2, Suf1, Pre2);
    tail1<<<dim3(75, 6), 256, 0, stream>>>(s1, rk1, Suf1, Pre2, W2T, a_src2, a_dst2, h2, s2, t2);
    // layer 2
    krank<<<dim3(38, 3, 8), 256, 0, stream>>>(s2, t2, rk2);
    phA<129, 384, 128, 1><<<dim3(240, 3), 256, 0, stream>>>(h2, rk2, t2, Tot1, Tot2);
    phC<129, 384, 128, 1><<<dim3(240, 3), 256, 0, stream>>>(h2, rk2, t2, Tot1, Tot2, Suf1, Pre2);
    tail2<<<75, 256, 0, stream>>>(s2, rk2, Suf1, Pre2, flat, P1T, P2T, b1, b2, out);
}

// Round 6
// 331.253 us; speedup vs baseline: 4.8849x; 1.0371x over previous
//
#include <hip/hip_runtime.h>
#include <hip/hip_bf16.h>

typedef __attribute__((ext_vector_type(8))) short short8;
typedef __attribute__((ext_vector_type(4))) float f32x4;

#define NN 4800
#define NN1 4801
#define NC 240
#define CL 20
#define KLEN 600

__device__ __forceinline__ short bf16rne(float x) {
    unsigned u = __float_as_uint(x);
    u = (u + 0x7FFFu + ((u >> 16) & 1u)) >> 16;
    return (short)u;
}
// monotonic float->uint key (ascending float == ascending uint)
__device__ __forceinline__ unsigned fkey(float f) {
    unsigned i = __float_as_uint(f);
    return (i & 0x80000000u) ? ~i : (i | 0x80000000u);
}

// ---------- prep: h1, weight transposes, s1/t1 dots, mask copy ----------
__global__ __launch_bounds__(256) void prep(
    const float* __restrict__ flat, const float* __restrict__ amask,
    const float* __restrict__ W1, const float* __restrict__ as1, const float* __restrict__ ad1,
    const float* __restrict__ W2, const float* __restrict__ P1, const float* __restrict__ P2,
    float* __restrict__ h1, float* __restrict__ s1, float* __restrict__ t1,
    short* __restrict__ W2T, short* __restrict__ P1T, short* __restrict__ P2T,
    float* __restrict__ out) {
    const int gtid = blockIdx.x * 256 + threadIdx.x;
    const int GT = 1200 * 256;
    for (int x = gtid; x < 1028832; x += GT) {
        if (x < 921600) {
            int i = x / 192, c = x % 192;
            const float* fr = flat + i * 15;
            float acc = 0.f;
#pragma unroll
            for (int f = 0; f < 15; ++f) acc += fr[f] * W1[f * 192 + c];
            h1[x] = acc;
        } else if (x < 995328) {
            int y = x - 921600; int n = y / 192, k = y % 192;
            W2T[y] = bf16rne(W2[k * 384 + n]);
        } else if (x < 1015808) {
            int z = x - 995328; int n = z / 160, k = z % 160;
            P1T[z] = bf16rne(k < 143 ? P1[k * 128 + n] : 0.f);
        } else if (x < 1024000) {
            int z = x - 1015808; int n = z / 128, k = z % 128;
            P2T[z] = bf16rne(P2[k * 64 + n]);
        } else {
            int m = x - 1024000;              // mask passthrough (4832)
            out[2048 + m] = amask[m];
        }
    }
    const int lane = threadIdx.x & 63;
    const int gw = (gtid >> 6);
    for (int task = gw; task < 3 * NN; task += (GT >> 6)) {
        int h = task / NN, i = task % NN;
        int col = h * 64 + lane;
        const float* fr = flat + i * 15;
        float hv = 0.f;
#pragma unroll
        for (int f = 0; f < 15; ++f) hv += fr[f] * W1[f * 192 + col];
        float ps = hv * as1[col], pt = hv * ad1[col];
#pragma unroll
        for (int off = 32; off; off >>= 1) { ps += __shfl_xor(ps, off); pt += __shfl_xor(pt, off); }
        if (lane == 0) { s1[h * NN + i] = ps; t1[h * NN + i] = pt; }
    }
}

// ---------- krank: rank counting (u32 keys, index tiebreak). grid (38,3,8) ----------
// rk[h][q<NN] = rank of t_q ; rk[h][NN+i] = #{j : t_j <= -s_i}
__global__ __launch_bounds__(256) void krank(const float* __restrict__ s, const float* __restrict__ t,
                                             int* __restrict__ rk) {
    __shared__ unsigned ts[KLEN];
    const int h = blockIdx.y, kc = blockIdx.z;
    const float* tp = t + h * NN + kc * KLEN;
    for (int k = threadIdx.x; k < KLEN; k += 256) ts[k] = fkey(tp[k]);
    __syncthreads();
    int q = blockIdx.x * 256 + threadIdx.x;
    if (q >= 2 * NN) return;
    unsigned u; int tb;
    if (q < NN) { u = fkey(t[h * NN + q]); tb = q - kc * KLEN; }   // local-index tiebreak
    else        { u = fkey(-s[h * NN + q - NN]); tb = KLEN; }      // <= semantics
    int cnt = 0;
#pragma unroll 8
    for (int k = 0; k < KLEN; ++k) {
        unsigned tk = ts[k];
        cnt += (tk < u) || (tk == u && k < tb);
    }
    atomicAdd(&rk[h * 2 * NN + q], cnt);
}

// ---------- kscan: inv + sorted exp tables + denominator scans. grid 3 ----------
__global__ __launch_bounds__(256) void kscan(const float* __restrict__ t, const int* __restrict__ rk,
                                             int* __restrict__ inv, float* __restrict__ e1s,
                                             float* __restrict__ e2s,
                                             float* __restrict__ DenS1, float* __restrict__ DenP2) {
    __shared__ float l1[NN], l2[NN];
    __shared__ float wsum[8];
    const int h = blockIdx.x, tid = threadIdx.x;
    for (int j = tid; j < NN; j += 256) {
        int r = rk[h * 2 * NN + j];
        float tv = t[h * NN + j];
        float a = __expf(tv), b = __expf(0.2f * tv);
        inv[h * NN + r] = j;
        e1s[h * NN + r] = a;
        e2s[h * NN + r] = b;
        l1[r] = a; l2[r] = b;
    }
    __syncthreads();
    const int p0 = tid * 19;
    const int cnt = (p0 < NN) ? ((NN - p0 < 19) ? NN - p0 : 19) : 0;
    float sA = 0.f, sB = 0.f;
    for (int k = 0; k < cnt; ++k) { sA += l1[p0 + k]; sB += l2[p0 + k]; }
    float iA = sA, iB = sB;
    const int lane = tid & 63, w = tid >> 6;
#pragma unroll
    for (int d2 = 1; d2 < 64; d2 <<= 1) {
        float uA = __shfl_up(iA, d2), uB = __shfl_up(iB, d2);
        if (lane >= d2) { iA += uA; iB += uB; }
    }
    if (lane == 63) { wsum[w] = iA; wsum[4 + w] = iB; }
    __syncthreads();
    float baseA = 0.f, baseB = 0.f;
    for (int k = 0; k < w; ++k) { baseA += wsum[k]; baseB += wsum[4 + k]; }
    float TA = wsum[0] + wsum[1] + wsum[2] + wsum[3];
    float rA = baseA + iA - sA;    // exclusive prefix offsets
    float rB = baseB + iB - sB;
    for (int k = 0; k < cnt; ++k) {
        int p = p0 + k;
        DenS1[h * NN1 + p] = TA - rA;   // inclusive suffix of e1
        DenP2[h * NN1 + p] = rB;        // exclusive prefix of e2
        rA += l1[p]; rB += l2[p];
    }
    if (tid == 255) {
        DenS1[h * NN1 + NN] = 0.f;
        DenP2[h * NN1 + NN] = wsum[4] + wsum[5] + wsum[6] + wsum[7];
    }
}

// ---------- phA: chunk totals. grid (NC/PACK, 3), PACK*Dd == 256 ----------
template <int Dd, int HD, int PACK>
__global__ __launch_bounds__(256) void phA(const float* __restrict__ hsrc, const int* __restrict__ inv,
                                           const float* __restrict__ e1s, const float* __restrict__ e2s,
                                           float* __restrict__ T1, float* __restrict__ T2) {
    __shared__ int inv_l[PACK * CL];
    __shared__ float w1s[PACK * CL], w2s[PACK * CL];
    const int h = blockIdx.y, tid = threadIdx.x;
    const int base = blockIdx.x * (PACK * CL);
    if (tid < PACK * CL) {
        inv_l[tid] = inv[h * NN + base + tid];
        w1s[tid] = e1s[h * NN + base + tid];
        w2s[tid] = e2s[h * NN + base + tid];
    }
    __syncthreads();
    const int sub = tid / Dd, d = tid % Dd;
    const int c = blockIdx.x * PACK + sub;
    float a1 = 0.f, a2 = 0.f;
#pragma unroll
    for (int p = 0; p < CL; ++p) {
        int j = inv_l[sub * CL + p];
        float hv = hsrc[(size_t)j * HD + h * Dd + d];
        a1 += w1s[sub * CL + p] * hv;
        a2 += w2s[sub * CL + p] * hv;
    }
    T1[(h * NC + c) * Dd + d] = a1;
    T2[(h * NC + c) * Dd + d] = a2;
}

// ---------- phB: scan chunk totals -> offsets (fp64 accumulator) ----------
template <int Dd>
__global__ __launch_bounds__(256) void phB(const float* __restrict__ T1, const float* __restrict__ T2,
                                           float* __restrict__ O1, float* __restrict__ O2) {
    int g = blockIdx.x * 256 + threadIdx.x;
    if (g >= 2 * 3 * Dd) return;
    int dir = g / (3 * Dd), rest = g % (3 * Dd), h = rest / Dd, d = rest % Dd;
    if (dir == 0) {           // suffix offsets (sum of chunks > c) for e1
        double r = 0; O1[(h * NC + NC - 1) * Dd + d] = 0.f;
#pragma unroll 8
        for (int c = NC - 2; c >= 0; --c) { r += (double)T1[(h * NC + c + 1) * Dd + d]; O1[(h * NC + c) * Dd + d] = (float)r; }
    } else {                  // prefix offsets (exclusive) for e2
        double r = 0; O2[h * NC * Dd + d] = 0.f;
#pragma unroll 8
        for (int c = 1; c < NC; ++c) { r += (double)T2[(h * NC + c - 1) * Dd + d]; O2[(h * NC + c) * Dd + d] = (float)r; }
    }
}

// ---------- phC: emit Suf1 (incl suffix, e1) / Pre2 (excl prefix, e2) ----------
template <int Dd, int HD, int PACK>
__global__ __launch_bounds__(256) void phC(const float* __restrict__ hsrc, const int* __restrict__ inv,
                                           const float* __restrict__ e1s, const float* __restrict__ e2s,
                                           const float* __restrict__ O1, const float* __restrict__ O2,
                                           float* __restrict__ Suf1, float* __restrict__ Pre2) {
    __shared__ int inv_l[PACK * CL];
    __shared__ float w1s[PACK * CL], w2s[PACK * CL];
    const int h = blockIdx.y, tid = threadIdx.x;
    const int base = blockIdx.x * (PACK * CL);
    if (tid < PACK * CL) {
        inv_l[tid] = inv[h * NN + base + tid];
        w1s[tid] = e1s[h * NN + base + tid];
        w2s[tid] = e2s[h * NN + base + tid];
    }
    __syncthreads();
    const int sub = tid / Dd, d = tid % Dd;
    const int c = blockIdx.x * PACK + sub;
    float hv[CL];
#pragma unroll
    for (int p = 0; p < CL; ++p) {
        int j = inv_l[sub * CL + p];
        hv[p] = hsrc[(size_t)j * HD + h * Dd + d];
    }
    float r2 = O2[(h * NC + c) * Dd + d];
#pragma unroll
    for (int p = 0; p < CL; ++p) {
        int pp = c * CL + p;
        Pre2[((size_t)(h * NN1) + pp) * Dd + d] = r2;
        r2 += w2s[sub * CL + p] * hv[p];
    }
    if (c == NC - 1) {
        Pre2[((size_t)(h * NN1) + NN) * Dd + d] = r2;
        Suf1[((size_t)(h * NN1) + NN) * Dd + d] = 0.f;
    }
    float r1 = O1[(h * NC + c) * Dd + d];
#pragma unroll
    for (int p = CL - 1; p >= 0; --p) {
        int pp = c * CL + p;
        r1 += w1s[sub * CL + p] * hv[p];
        Suf1[((size_t)(h * NN1) + pp) * Dd + d] = r1;
    }
}

// ---------- TAIL1: kout1 + gemm h2 (all 6 N-tiles) + s2/t2 dots. grid 75 ----------
__global__ __launch_bounds__(256) void tail1(
    const float* __restrict__ s1, const int* __restrict__ rk1,
    const float* __restrict__ Suf1, const float* __restrict__ Pre2,
    const float* __restrict__ DenS1, const float* __restrict__ DenP2,
    const short* __restrict__ W2T, const float* __restrict__ as2, const float* __restrict__ ad2,
    float* __restrict__ h2, float* __restrict__ s2, float* __restrict__ t2) {
    __shared__ short At[64][200];
    __shared__ float s2l[192], t2l[192];
    const int mb = blockIdx.x, tid = threadIdx.x;
    if (tid < 192) { s2l[tid] = 0.f; t2l[tid] = 0.f; }
    for (int e = tid; e < 64 * 192; e += 256) {   // kout1 for this row-tile
        int row = e / 192, cc = e % 192;
        int i = mb * 64 + row, h = cc >> 6, d = cc & 63;
        float sv = s1[h * NN + i];
        float a = __expf(sv), b = __expf(0.2f * sv);
        int r = rk1[h * 2 * NN + NN + i];
        size_t bp = ((size_t)(h * NN1) + r) * 64 + d;
        float num = a * Suf1[bp] + b * Pre2[bp];
        float den = a * DenS1[h * NN1 + r] + b * DenP2[h * NN1 + r];
        float v = num / den;
        v = v > 0.f ? v : (__expf(v) - 1.f);      // ELU
        At[row][cc] = bf16rne(v);
    }
    __syncthreads();
    const int lane = tid & 63, w = tid >> 6, q = lane >> 4, mr = lane & 15;
    for (int nb = 0; nb < 6; ++nb) {
        const int n0 = nb * 64, hh = nb >> 1;
        f32x4 acc[4];
#pragma unroll
        for (int n = 0; n < 4; ++n) acc[n] = (f32x4){0.f, 0.f, 0.f, 0.f};
#pragma unroll
        for (int k0 = 0; k0 < 192; k0 += 32) {
            short8 af = *(const short8*)&At[w * 16 + mr][k0 + q * 8];
#pragma unroll
            for (int n = 0; n < 4; ++n) {
                short8 bf = *(const short8*)(W2T + (size_t)(n0 + n * 16 + mr) * 192 + k0 + q * 8);
                acc[n] = __builtin_amdgcn_mfma_f32_16x16x32_bf16(af, bf, acc[n], 0, 0, 0);
            }
        }
        float pse[4] = {0.f, 0.f, 0.f, 0.f}, pte[4] = {0.f, 0.f, 0.f, 0.f};
#pragma unroll
        for (int n = 0; n < 4; ++n) {
            int col = n0 + n * 16 + mr;
            float va = as2[col], vd = ad2[col];
#pragma unroll
            for (int r = 0; r < 4; ++r) {
                int row = mb * 64 + w * 16 + q * 4 + r;
                float v = acc[n][r];
                h2[(size_t)row * 384 + col] = v;
                pse[r] += v * va;
                pte[r] += v * vd;
            }
        }
#pragma unroll
        for (int off = 1; off < 16; off <<= 1) {
#pragma unroll
            for (int r = 0; r < 4; ++r) {
                pse[r] += __shfl_xor(pse[r], off);
                pte[r] += __shfl_xor(pte[r], off);
            }
        }
        if (mr == 0) {
#pragma unroll
            for (int r = 0; r < 4; ++r) {
                int lrow = w * 16 + q * 4 + r;
                s2l[hh * 64 + lrow] += pse[r];    // unique owner lane per (hh,lrow)
                t2l[hh * 64 + lrow] += pte[r];
            }
        }
    }
    __syncthreads();
    if (tid < 192) {
        int h = tid >> 6, row = tid & 63;
        s2[h * NN + mb * 64 + row] = s2l[tid];
        t2[h * NN + mb * 64 + row] = t2l[tid];
    }
}

// ---------- TAIL2: kout2 + F1 + F2 + mean pool. grid 75 ----------
__global__ __launch_bounds__(256) void tail2(
    const float* __restrict__ s2, const int* __restrict__ rk2,
    const float* __restrict__ Suf1, const float* __restrict__ Pre2,
    const float* __restrict__ DenS1, const float* __restrict__ DenP2,
    const float* __restrict__ flat, const short* __restrict__ P1T, const short* __restrict__ P2T,
    const float* __restrict__ b1, const float* __restrict__ b2,
    float* __restrict__ out) {
    __shared__ short g[64][168];
    __shared__ short f1[64][136];
    const int mb = blockIdx.x, tid = threadIdx.x;
    for (int e = tid; e < 64 * 160; e += 256) {   // build g tile
        int row = e / 160, c = e % 160;
        int i = mb * 64 + row;
        float v;
        if (c < 128) {
            float acc = 0.f;
#pragma unroll
            for (int h = 0; h < 3; ++h) {
                float sv = s2[h * NN + i];
                float a = __expf(sv), b = __expf(0.2f * sv);
                int r = rk2[h * 2 * NN + NN + i];
                size_t bp = ((size_t)(h * NN1) + r) * 128 + c;
                float num = a * Suf1[bp] + b * Pre2[bp];
                float den = a * DenS1[h * NN1 + r] + b * DenP2[h * NN1 + r];
                acc += num / den;
            }
            v = acc * (1.f / 3.f);
        } else if (c < 143) v = flat[i * 15 + (c - 128)];
        else v = 0.f;
        g[row][c] = bf16rne(v);
    }
    __syncthreads();
    const int lane = tid & 63, w = tid >> 6, q = lane >> 4, mr = lane & 15;
    f32x4 a1[8];
#pragma unroll
    for (int n = 0; n < 8; ++n) a1[n] = (f32x4){0.f, 0.f, 0.f, 0.f};
#pragma unroll
    for (int k0 = 0; k0 < 160; k0 += 32) {
        short8 af = *(const short8*)&g[w * 16 + mr][k0 + q * 8];
#pragma unroll
        for (int n = 0; n < 8; ++n) {
            short8 bf = *(const short8*)(P1T + (size_t)(n * 16 + mr) * 160 + k0 + q * 8);
            a1[n] = __builtin_amdgcn_mfma_f32_16x16x32_bf16(af, bf, a1[n], 0, 0, 0);
        }
    }
#pragma unroll
    for (int n = 0; n < 8; ++n) {
        int col = n * 16 + mr;
        float bv = b1[col];
#pragma unroll
        for (int r = 0; r < 4; ++r) {
            int row = w * 16 + q * 4 + r;
            f1[row][col] = bf16rne(fmaxf(a1[n][r] + bv, 0.f));
        }
    }
    __syncthreads();
    f32x4 a2[4];
#pragma unroll
    for (int n = 0; n < 4; ++n) a2[n] = (f32x4){0.f, 0.f, 0.f, 0.f};
#pragma unroll
    for (int k0 = 0; k0 < 128; k0 += 32) {
        short8 af = *(const short8*)&f1[w * 16 + mr][k0 + q * 8];
#pragma unroll
        for (int n = 0; n < 4; ++n) {
            short8 bf = *(const short8*)(P2T + (size_t)(n * 16 + mr) * 128 + k0 + q * 8);
            a2[n] = __builtin_amdgcn_mfma_f32_16x16x32_bf16(af, bf, a2[n], 0, 0, 0);
        }
    }
    float* f2f = (float*)&g[0][0];                 // reuse g LDS: 64*65*4 = 16.6 KB <= 21 KB
#pragma unroll
    for (int n = 0; n < 4; ++n) {
        int col = n * 16 + mr;
        float bv = b2[col];
#pragma unroll
        for (int r = 0; r < 4; ++r) {
            int row = w * 16 + q * 4 + r;
            f2f[row * 65 + col] = fmaxf(a2[n][r] + bv, 0.f);
        }
    }
    __syncthreads();
    if (tid < 64) {                                // mean pool (atomics into zeroed out)
        int d = tid;
        int b0 = (mb * 64) / 150;
        int bend = (mb * 64 + 63) / 150;
        float sa = 0.f, sb = 0.f;
        for (int row = 0; row < 64; ++row) {
            float v = f2f[row * 65 + d];
            int b = (mb * 64 + row) / 150;
            if (b == b0) sa += v; else sb += v;
        }
        atomicAdd(&out[b0 * 64 + d], sa * (1.f / 150.f));
        if (bend != b0) atomicAdd(&out[bend * 64 + d], sb * (1.f / 150.f));
    }
}

extern "C" void kernel_launch(void* const* d_in, const int* in_sizes, int n_in,
                              void* d_out, int out_size, void* d_ws, size_t ws_size,
                              hipStream_t stream) {
    const float* flat   = (const float*)d_in[0];
    const float* amask  = (const float*)d_in[1];
    const float* W1     = (const float*)d_in[2];
    const float* a_src1 = (const float*)d_in[3];
    const float* a_dst1 = (const float*)d_in[4];
    const float* W2     = (const float*)d_in[5];
    const float* a_src2 = (const float*)d_in[6];
    const float* a_dst2 = (const float*)d_in[7];
    const float* P1     = (const float*)d_in[8];
    const float* b1     = (const float*)d_in[9];
    const float* P2     = (const float*)d_in[10];
    const float* b2     = (const float*)d_in[11];
    float* out = (float*)d_out;

    char* wsb = (char*)d_ws;
    int*   rk1   = (int*)  (wsb + 0);          // 115200; memset [0,230400)
    int*   rk2   = (int*)  (wsb + 115200);     // 115200
    float* s1    = (float*)(wsb + 230400);     // 57600
    float* t1    = (float*)(wsb + 288000);
    float* s2    = (float*)(wsb + 345600);
    float* t2    = (float*)(wsb + 403200);
    float* h1    = (float*)(wsb + 460800);     // 3686400
    int*   inv   = (int*)  (wsb + 4147200);    // 57600
    float* e1s   = (float*)(wsb + 4204800);    // 57600
    float* e2s   = (float*)(wsb + 4262400);    // 57600
    float* DenS1 = (float*)(wsb + 4320000);    // 57664 (3*4801*4 pad)
    float* DenP2 = (float*)(wsb + 4377664);    // 57664
    float* Tot1  = (float*)(wsb + 4435328);    // 368640 (3*240*128*4)
    float* Tot2  = (float*)(wsb + 4803968);
    float* Off1  = (float*)(wsb + 5172608);
    float* Off2  = (float*)(wsb + 5541248);
    float* Suf1  = (float*)(wsb + 5909888);    // 7374336 (3*4801*128*4)
    float* Pre2  = (float*)(wsb + 13284224);   // 7374336
    float* h2    = (float*)(wsb + 20658560);   // 7372800
    short* W2T   = (short*)(wsb + 28031360);   // 147456
    short* P1T   = (short*)(wsb + 28178816);   // 40960
    short* P2T   = (short*)(wsb + 28219776);   // 16384 -> end 28236160

    hipMemsetAsync(d_ws, 0, 230400, stream);      // rk1, rk2
    hipMemsetAsync(d_out, 0, 2048 * 4, stream);   // pool accumulators

    prep<<<1200, 256, 0, stream>>>(flat, amask, W1, a_src1, a_dst1, W2, P1, P2,
                                   h1, s1, t1, W2T, P1T, P2T, out);
    // layer 1 (Dd=64, HD=192, PACK=4)
    krank<<<dim3(38, 3, 8), 256, 0, stream>>>(s1, t1, rk1);
    kscan<<<3, 256, 0, stream>>>(t1, rk1, inv, e1s, e2s, DenS1, DenP2);
    phA<64, 192, 4><<<dim3(60, 3), 256, 0, stream>>>(h1, inv, e1s, e2s, Tot1, Tot2);
    phB<64><<<2, 256, 0, stream>>>(Tot1, Tot2, Off1, Off2);
    phC<64, 192, 4><<<dim3(60, 3), 256, 0, stream>>>(h1, inv, e1s, e2s, Off1, Off2, Suf1, Pre2);
    tail1<<<75, 256, 0, stream>>>(s1, rk1, Suf1, Pre2, DenS1, DenP2, W2T, a_src2, a_dst2, h2, s2, t2);
    // layer 2 (Dd=128, HD=384, PACK=2)
    krank<<<dim3(38, 3, 8), 256, 0, stream>>>(s2, t2, rk2);
    kscan<<<3, 256, 0, stream>>>(t2, rk2, inv, e1s, e2s, DenS1, DenP2);
    phA<128, 384, 2><<<dim3(120, 3), 256, 0, stream>>>(h2, inv, e1s, e2s, Tot1, Tot2);
    phB<128><<<3, 256, 0, stream>>>(Tot1, Tot2, Off1, Off2);
    phC<128, 384, 2><<<dim3(120, 3), 256, 0, stream>>>(h2, inv, e1s, e2s, Off1, Off2, Suf1, Pre2);
    tail2<<<75, 256, 0, stream>>>(s2, rk2, Suf1, Pre2, DenS1, DenP2, flat, P1T, P2T, b1, b2, out);
}

// Round 7
// 310.534 us; speedup vs baseline: 5.2108x; 1.0667x over previous
//
#include <hip/hip_runtime.h>
#include <hip/hip_bf16.h>

typedef __attribute__((ext_vector_type(8))) short short8;
typedef __attribute__((ext_vector_type(4))) float f32x4;

#define NN 4800
#define NN1 4801
#define NC 240
#define CL 20
#define KLEN 600

__device__ __forceinline__ short bf16rne(float x) {
    unsigned u = __float_as_uint(x);
    u = (u + 0x7FFFu + ((u >> 16) & 1u)) >> 16;
    return (short)u;
}
// monotonic float->uint key (ascending float == ascending uint)
__device__ __forceinline__ unsigned fkey(float f) {
    unsigned i = __float_as_uint(f);
    return (i & 0x80000000u) ? ~i : (i | 0x80000000u);
}

// ---------- prep: h1, weight transposes, s1/t1 dots, mask copy, out zero ----------
__global__ __launch_bounds__(256) void prep(
    const float* __restrict__ flat, const float* __restrict__ amask,
    const float* __restrict__ W1, const float* __restrict__ as1, const float* __restrict__ ad1,
    const float* __restrict__ W2, const float* __restrict__ P1, const float* __restrict__ P2,
    float* __restrict__ h1, float* __restrict__ s1, float* __restrict__ t1,
    short* __restrict__ W2T, short* __restrict__ P1T, short* __restrict__ P2T,
    float* __restrict__ out) {
    const int gtid = blockIdx.x * 256 + threadIdx.x;
    const int GT = 1200 * 256;
    for (int x = gtid; x < 1030880; x += GT) {
        if (x < 921600) {
            int i = x / 192, c = x % 192;
            const float* fr = flat + i * 15;
            float acc = 0.f;
#pragma unroll
            for (int f = 0; f < 15; ++f) acc += fr[f] * W1[f * 192 + c];
            h1[x] = acc;
        } else if (x < 995328) {
            int y = x - 921600; int n = y / 192, k = y % 192;
            W2T[y] = bf16rne(W2[k * 384 + n]);
        } else if (x < 1015808) {
            int z = x - 995328; int n = z / 160, k = z % 160;
            P1T[z] = bf16rne(k < 143 ? P1[k * 128 + n] : 0.f);
        } else if (x < 1024000) {
            int z = x - 1015808; int n = z / 128, k = z % 128;
            P2T[z] = bf16rne(P2[k * 64 + n]);
        } else if (x < 1028832) {
            int m = x - 1024000;              // mask passthrough (4832)
            out[2048 + m] = amask[m];
        } else {
            out[x - 1028832] = 0.f;           // pool accumulators
        }
    }
    const int lane = threadIdx.x & 63;
    const int gw = (gtid >> 6);
    for (int task = gw; task < 3 * NN; task += (GT >> 6)) {
        int h = task / NN, i = task % NN;
        int col = h * 64 + lane;
        const float* fr = flat + i * 15;
        float hv = 0.f;
#pragma unroll
        for (int f = 0; f < 15; ++f) hv += fr[f] * W1[f * 192 + col];
        float ps = hv * as1[col], pt = hv * ad1[col];
#pragma unroll
        for (int off = 32; off; off >>= 1) { ps += __shfl_xor(ps, off); pt += __shfl_xor(pt, off); }
        if (lane == 0) { s1[h * NN + i] = ps; t1[h * NN + i] = pt; }
    }
}

// ---------- krank: partial rank counts of t-keys only. grid (19,3,8) ----------
__global__ __launch_bounds__(256) void krank(const float* __restrict__ t, int* __restrict__ partial) {
    __shared__ __align__(16) unsigned ts[KLEN];
    const int h = blockIdx.y, kc = blockIdx.z;
    const float* tp = t + h * NN + kc * KLEN;
    for (int k = threadIdx.x; k < KLEN; k += 256) ts[k] = fkey(tp[k]);
    __syncthreads();
    int q = blockIdx.x * 256 + threadIdx.x;
    if (q >= NN) return;
    unsigned u = fkey(t[h * NN + q]);
    int tb = q - kc * KLEN;                  // local-index tiebreak
    int cnt = 0;
#pragma unroll 2
    for (int k = 0; k < KLEN; k += 4) {
        uint4 v = *(const uint4*)&ts[k];
        cnt += (v.x < u) || (v.x == u && (k + 0) < tb);
        cnt += (v.y < u) || (v.y == u && (k + 1) < tb);
        cnt += (v.z < u) || (v.z == u && (k + 2) < tb);
        cnt += (v.w < u) || (v.w == u && (k + 3) < tb);
    }
    partial[(kc * 3 + h) * NN + q] = cnt;
}

// ---------- kscan: sum partials -> inv/exp tables/den scans + s-rank binary search. grid 3 ----------
__global__ __launch_bounds__(256) void kscan(const float* __restrict__ t, const float* __restrict__ s,
                                             const int* __restrict__ partial,
                                             int* __restrict__ inv, float* __restrict__ e1s,
                                             float* __restrict__ e2s,
                                             float* __restrict__ DenS1, float* __restrict__ DenP2,
                                             int* __restrict__ rks) {
    __shared__ float l1[NN], l2[NN];
    __shared__ unsigned skey[NN];
    __shared__ float wsum[8];
    const int h = blockIdx.x, tid = threadIdx.x;
    for (int j = tid; j < NN; j += 256) {
        int r = 0;
#pragma unroll
        for (int kc = 0; kc < 8; ++kc) r += partial[(kc * 3 + h) * NN + j];
        float tv = t[h * NN + j];
        float a = __expf(tv), b = __expf(0.2f * tv);
        inv[h * NN + r] = j;
        e1s[h * NN + r] = a;
        e2s[h * NN + r] = b;
        l1[r] = a; l2[r] = b;
        skey[r] = fkey(tv);
    }
    __syncthreads();
    // s-query ranks: #{j: t_j <= -s_i} = upper_bound(skey, fkey(-s_i))
    for (int i = tid; i < NN; i += 256) {
        unsigned u2 = fkey(-s[h * NN + i]);
        int lo = 0, hi = NN;
        while (lo < hi) { int mid = (lo + hi) >> 1; if (skey[mid] <= u2) lo = mid + 1; else hi = mid; }
        rks[h * NN + i] = lo;
    }
    // denominator scans
    const int p0 = tid * 19;
    const int cnt = (p0 < NN) ? ((NN - p0 < 19) ? NN - p0 : 19) : 0;
    float sA = 0.f, sB = 0.f;
    for (int k = 0; k < cnt; ++k) { sA += l1[p0 + k]; sB += l2[p0 + k]; }
    float iA = sA, iB = sB;
    const int lane = tid & 63, w = tid >> 6;
#pragma unroll
    for (int d2 = 1; d2 < 64; d2 <<= 1) {
        float uA = __shfl_up(iA, d2), uB = __shfl_up(iB, d2);
        if (lane >= d2) { iA += uA; iB += uB; }
    }
    if (lane == 63) { wsum[w] = iA; wsum[4 + w] = iB; }
    __syncthreads();
    float baseA = 0.f, baseB = 0.f;
    for (int k = 0; k < w; ++k) { baseA += wsum[k]; baseB += wsum[4 + k]; }
    float TA = wsum[0] + wsum[1] + wsum[2] + wsum[3];
    float rA = baseA + iA - sA;    // exclusive prefix offsets
    float rB = baseB + iB - sB;
    for (int k = 0; k < cnt; ++k) {
        int p = p0 + k;
        DenS1[h * NN1 + p] = TA - rA;   // inclusive suffix of e1
        DenP2[h * NN1 + p] = rB;        // exclusive prefix of e2
        rA += l1[p]; rB += l2[p];
    }
    if (tid == 255) {
        DenS1[h * NN1 + NN] = 0.f;
        DenP2[h * NN1 + NN] = wsum[4] + wsum[5] + wsum[6] + wsum[7];
    }
}

// ---------- phA: chunk totals. grid (NC/PACK, 3), PACK*Dd == 256 ----------
template <int Dd, int HD, int PACK>
__global__ __launch_bounds__(256) void phA(const float* __restrict__ hsrc, const int* __restrict__ inv,
                                           const float* __restrict__ e1s, const float* __restrict__ e2s,
                                           float* __restrict__ T1, float* __restrict__ T2) {
    __shared__ int inv_l[PACK * CL];
    __shared__ float w1s[PACK * CL], w2s[PACK * CL];
    const int h = blockIdx.y, tid = threadIdx.x;
    const int base = blockIdx.x * (PACK * CL);
    if (tid < PACK * CL) {
        inv_l[tid] = inv[h * NN + base + tid];
        w1s[tid] = e1s[h * NN + base + tid];
        w2s[tid] = e2s[h * NN + base + tid];
    }
    __syncthreads();
    const int sub = tid / Dd, d = tid % Dd;
    const int c = blockIdx.x * PACK + sub;
    float a1 = 0.f, a2 = 0.f;
#pragma unroll
    for (int p = 0; p < CL; ++p) {
        int j = inv_l[sub * CL + p];
        float hv = hsrc[(size_t)j * HD + h * Dd + d];
        a1 += w1s[sub * CL + p] * hv;
        a2 += w2s[sub * CL + p] * hv;
    }
    T1[(h * NC + c) * Dd + d] = a1;
    T2[(h * NC + c) * Dd + d] = a2;
}

// ---------- phB: scan chunk totals -> offsets (fp64 accumulator) ----------
template <int Dd>
__global__ __launch_bounds__(256) void phB(const float* __restrict__ T1, const float* __restrict__ T2,
                                           float* __restrict__ O1, float* __restrict__ O2) {
    int g = blockIdx.x * 256 + threadIdx.x;
    if (g >= 2 * 3 * Dd) return;
    int dir = g / (3 * Dd), rest = g % (3 * Dd), h = rest / Dd, d = rest % Dd;
    if (dir == 0) {
        double r = 0; O1[(h * NC + NC - 1) * Dd + d] = 0.f;
#pragma unroll 8
        for (int c = NC - 2; c >= 0; --c) { r += (double)T1[(h * NC + c + 1) * Dd + d]; O1[(h * NC + c) * Dd + d] = (float)r; }
    } else {
        double r = 0; O2[h * NC * Dd + d] = 0.f;
#pragma unroll 8
        for (int c = 1; c < NC; ++c) { r += (double)T2[(h * NC + c - 1) * Dd + d]; O2[(h * NC + c) * Dd + d] = (float)r; }
    }
}

// ---------- phC: emit Suf1 (incl suffix, e1) / Pre2 (excl prefix, e2) ----------
template <int Dd, int HD, int PACK>
__global__ __launch_bounds__(256) void phC(const float* __restrict__ hsrc, const int* __restrict__ inv,
                                           const float* __restrict__ e1s, const float* __restrict__ e2s,
                                           const float* __restrict__ O1, const float* __restrict__ O2,
                                           float* __restrict__ Suf1, float* __restrict__ Pre2) {
    __shared__ int inv_l[PACK * CL];
    __shared__ float w1s[PACK * CL], w2s[PACK * CL];
    const int h = blockIdx.y, tid = threadIdx.x;
    const int base = blockIdx.x * (PACK * CL);
    if (tid < PACK * CL) {
        inv_l[tid] = inv[h * NN + base + tid];
        w1s[tid] = e1s[h * NN + base + tid];
        w2s[tid] = e2s[h * NN + base + tid];
    }
    __syncthreads();
    const int sub = tid / Dd, d = tid % Dd;
    const int c = blockIdx.x * PACK + sub;
    float hv[CL];
#pragma unroll
    for (int p = 0; p < CL; ++p) {
        int j = inv_l[sub * CL + p];
        hv[p] = hsrc[(size_t)j * HD + h * Dd + d];
    }
    float r2 = O2[(h * NC + c) * Dd + d];
#pragma unroll
    for (int p = 0; p < CL; ++p) {
        int pp = c * CL + p;
        Pre2[((size_t)(h * NN1) + pp) * Dd + d] = r2;
        r2 += w2s[sub * CL + p] * hv[p];
    }
    if (c == NC - 1) {
        Pre2[((size_t)(h * NN1) + NN) * Dd + d] = r2;
        Suf1[((size_t)(h * NN1) + NN) * Dd + d] = 0.f;
    }
    float r1 = O1[(h * NC + c) * Dd + d];
#pragma unroll
    for (int p = CL - 1; p >= 0; --p) {
        int pp = c * CL + p;
        r1 += w1s[sub * CL + p] * hv[p];
        Suf1[((size_t)(h * NN1) + pp) * Dd + d] = r1;
    }
}

// ---------- kout1: combine + ELU -> h1abf; zero s2/t2. grid 300 ----------
__global__ __launch_bounds__(256) void kout1(const float* __restrict__ s1, const int* __restrict__ rks1,
                                             const float* __restrict__ Suf1, const float* __restrict__ Pre2,
                                             const float* __restrict__ DenS1, const float* __restrict__ DenP2,
                                             short* __restrict__ h1abf,
                                             float* __restrict__ s2, float* __restrict__ t2) {
    const int gtid = blockIdx.x * 256 + threadIdx.x;
    if (gtid < 3 * NN) { s2[gtid] = 0.f; t2[gtid] = 0.f; }
    for (int x = gtid; x < NN * 192; x += 300 * 256) {
        int i = x / 192, cc = x % 192, h = cc >> 6, d = cc & 63;
        float sv = s1[h * NN + i];
        float a = __expf(sv), b = __expf(0.2f * sv);
        int r = rks1[h * NN + i];
        size_t bp = ((size_t)(h * NN1) + r) * 64 + d;
        float num = a * Suf1[bp] + b * Pre2[bp];
        float den = a * DenS1[h * NN1 + r] + b * DenP2[h * NN1 + r];
        float v = num / den;
        v = v > 0.f ? v : (__expf(v) - 1.f);      // ELU
        h1abf[x] = bf16rne(v);
    }
}

// ---------- gemm1: h2 = h1a @ W2 + fused s2/t2 dots. grid (75,6) ----------
__global__ __launch_bounds__(256) void gemm1(const short* __restrict__ A, const short* __restrict__ W2T,
                                             const float* __restrict__ as2, const float* __restrict__ ad2,
                                             float* __restrict__ h2, float* __restrict__ s2,
                                             float* __restrict__ t2) {
    const int mb = blockIdx.x, nb = blockIdx.y, tid = threadIdx.x;
    const int lane = tid & 63, w = tid >> 6, q = lane >> 4, mr = lane & 15;
    const int m = mb * 64 + w * 16 + mr, n0 = nb * 64, hh = nb >> 1;
    f32x4 acc[4];
#pragma unroll
    for (int n = 0; n < 4; ++n) acc[n] = (f32x4){0.f, 0.f, 0.f, 0.f};
#pragma unroll
    for (int k0 = 0; k0 < 192; k0 += 32) {
        short8 af = *(const short8*)(A + (size_t)m * 192 + k0 + q * 8);
#pragma unroll
        for (int n = 0; n < 4; ++n) {
            short8 bf = *(const short8*)(W2T + (size_t)(n0 + n * 16 + mr) * 192 + k0 + q * 8);
            acc[n] = __builtin_amdgcn_mfma_f32_16x16x32_bf16(af, bf, acc[n], 0, 0, 0);
        }
    }
    float pse[4] = {0.f, 0.f, 0.f, 0.f}, pte[4] = {0.f, 0.f, 0.f, 0.f};
#pragma unroll
    for (int n = 0; n < 4; ++n) {
        int col = n0 + n * 16 + mr;
        float va = as2[col], vd = ad2[col];
#pragma unroll
        for (int r = 0; r < 4; ++r) {
            int row = mb * 64 + w * 16 + q * 4 + r;
            float v = acc[n][r];
            h2[(size_t)row * 384 + col] = v;
            pse[r] += v * va;
            pte[r] += v * vd;
        }
    }
#pragma unroll
    for (int off = 1; off < 16; off <<= 1) {
#pragma unroll
        for (int r = 0; r < 4; ++r) {
            pse[r] += __shfl_xor(pse[r], off);
            pte[r] += __shfl_xor(pte[r], off);
        }
    }
    if (mr == 0) {
#pragma unroll
        for (int r = 0; r < 4; ++r) {
            int row = mb * 64 + w * 16 + q * 4 + r;
            atomicAdd(&s2[hh * NN + row], pse[r]);
            atomicAdd(&t2[hh * NN + row], pte[r]);
        }
    }
}

// ---------- TAIL2: kout2 + F1 + F2 + mean pool. grid 150 (M=32) ----------
__global__ __launch_bounds__(256) void tail2(
    const float* __restrict__ s2, const int* __restrict__ rks2,
    const float* __restrict__ Suf1, const float* __restrict__ Pre2,
    const float* __restrict__ DenS1, const float* __restrict__ DenP2,
    const float* __restrict__ flat, const short* __restrict__ P1T, const short* __restrict__ P2T,
    const float* __restrict__ b1, const float* __restrict__ b2,
    float* __restrict__ out) {
    __shared__ short g[32][168];
    __shared__ short f1[32][136];
    const int mb = blockIdx.x, tid = threadIdx.x;
    for (int e = tid; e < 32 * 160; e += 256) {   // build g tile
        int row = e / 160, c = e % 160;
        int i = mb * 32 + row;
        float v;
        if (c < 128) {
            float acc = 0.f;
#pragma unroll
            for (int h = 0; h < 3; ++h) {
                float sv = s2[h * NN + i];
                float a = __expf(sv), b = __expf(0.2f * sv);
                int r = rks2[h * NN + i];
                size_t bp = ((size_t)(h * NN1) + r) * 128 + c;
                float num = a * Suf1[bp] + b * Pre2[bp];
                float den = a * DenS1[h * NN1 + r] + b * DenP2[h * NN1 + r];
                acc += num / den;
            }
            v = acc * (1.f / 3.f);
        } else if (c < 143) v = flat[i * 15 + (c - 128)];
        else v = 0.f;
        g[row][c] = bf16rne(v);
    }
    __syncthreads();
    const int lane = tid & 63, w = tid >> 6, q = lane >> 4, mr = lane & 15;
    const int s_ = w & 1;       // M-stripe (16 rows)
    const int ch = w >> 1;      // col-half
    // F1: rows s_*16.., cols ch*64.., K=160
    f32x4 a1[4];
#pragma unroll
    for (int n = 0; n < 4; ++n) a1[n] = (f32x4){0.f, 0.f, 0.f, 0.f};
#pragma unroll
    for (int k0 = 0; k0 < 160; k0 += 32) {
        short8 af = *(const short8*)&g[s_ * 16 + mr][k0 + q * 8];
#pragma unroll
        for (int n = 0; n < 4; ++n) {
            short8 bf = *(const short8*)(P1T + (size_t)(ch * 64 + n * 16 + mr) * 160 + k0 + q * 8);
            a1[n] = __builtin_amdgcn_mfma_f32_16x16x32_bf16(af, bf, a1[n], 0, 0, 0);
        }
    }
#pragma unroll
    for (int n = 0; n < 4; ++n) {
        int col = ch * 64 + n * 16 + mr;
        float bv = b1[col];
#pragma unroll
        for (int r = 0; r < 4; ++r) {
            int row = s_ * 16 + q * 4 + r;
            f1[row][col] = bf16rne(fmaxf(a1[n][r] + bv, 0.f));
        }
    }
    __syncthreads();
    // F2: rows s_*16.., ntiles ch*2..ch*2+2, K=128
    f32x4 a2[2];
#pragma unroll
    for (int n = 0; n < 2; ++n) a2[n] = (f32x4){0.f, 0.f, 0.f, 0.f};
#pragma unroll
    for (int k0 = 0; k0 < 128; k0 += 32) {
        short8 af = *(const short8*)&f1[s_ * 16 + mr][k0 + q * 8];
#pragma unroll
        for (int n = 0; n < 2; ++n) {
            short8 bf = *(const short8*)(P2T + (size_t)((ch * 2 + n) * 16 + mr) * 128 + k0 + q * 8);
            a2[n] = __builtin_amdgcn_mfma_f32_16x16x32_bf16(af, bf, a2[n], 0, 0, 0);
        }
    }
    float* f2f = (float*)&g[0][0];                 // reuse g LDS: 32*65*4 = 8.3 KB
#pragma unroll
    for (int n = 0; n < 2; ++n) {
        int col = (ch * 2 + n) * 16 + mr;
        float bv = b2[col];
#pragma unroll
        for (int r = 0; r < 4; ++r) {
            int row = s_ * 16 + q * 4 + r;
            f2f[row * 65 + col] = fmaxf(a2[n][r] + bv, 0.f);
        }
    }
    __syncthreads();
    if (tid < 64) {                                // mean pool (atomics into zeroed out)
        int d = tid;
        int b0 = (mb * 32) / 150;
        int bend = (mb * 32 + 31) / 150;
        float sa = 0.f, sb = 0.f;
        for (int row = 0; row < 32; ++row) {
            float v = f2f[row * 65 + d];
            int b = (mb * 32 + row) / 150;
            if (b == b0) sa += v; else sb += v;
        }
        atomicAdd(&out[b0 * 64 + d], sa * (1.f / 150.f));
        if (bend != b0) atomicAdd(&out[bend * 64 + d], sb * (1.f / 150.f));
    }
}

extern "C" void kernel_launch(void* const* d_in, const int* in_sizes, int n_in,
                              void* d_out, int out_size, void* d_ws, size_t ws_size,
                              hipStream_t stream) {
    const float* flat   = (const float*)d_in[0];
    const float* amask  = (const float*)d_in[1];
    const float* W1     = (const float*)d_in[2];
    const float* a_src1 = (const float*)d_in[3];
    const float* a_dst1 = (const float*)d_in[4];
    const float* W2     = (const float*)d_in[5];
    const float* a_src2 = (const float*)d_in[6];
    const float* a_dst2 = (const float*)d_in[7];
    const float* P1     = (const float*)d_in[8];
    const float* b1     = (const float*)d_in[9];
    const float* P2     = (const float*)d_in[10];
    const float* b2     = (const float*)d_in[11];
    float* out = (float*)d_out;

    char* wsb = (char*)d_ws;
    int*   partial = (int*)  (wsb + 0);         // 8*3*4800*4 = 460800
    float* s1      = (float*)(wsb + 460800);    // 57600
    float* t1      = (float*)(wsb + 518400);
    float* s2      = (float*)(wsb + 576000);
    float* t2      = (float*)(wsb + 633600);
    int*   rks1    = (int*)  (wsb + 691200);    // 57600
    int*   rks2    = (int*)  (wsb + 748800);
    float* h1      = (float*)(wsb + 806400);    // 3686400
    int*   inv     = (int*)  (wsb + 4492800);   // 57600
    float* e1s     = (float*)(wsb + 4550400);
    float* e2s     = (float*)(wsb + 4608000);
    float* DenS1   = (float*)(wsb + 4665600);   // 57664
    float* DenP2   = (float*)(wsb + 4723264);   // 57664
    float* Tot1    = (float*)(wsb + 4780928);   // 368640
    float* Tot2    = (float*)(wsb + 5149568);
    float* Off1    = (float*)(wsb + 5518208);
    float* Off2    = (float*)(wsb + 5886848);
    float* Suf1    = (float*)(wsb + 6255488);   // 7374336
    float* Pre2    = (float*)(wsb + 13629824);  // 7374336
    float* h2      = (float*)(wsb + 21004160);  // 7372800
    short* h1abf   = (short*)(wsb + 28376960);  // 1843200
    short* W2T     = (short*)(wsb + 30220160);  // 147456
    short* P1T     = (short*)(wsb + 30367616);  // 40960
    short* P2T     = (short*)(wsb + 30408576);  // 16384 -> end 30424960

    prep<<<1200, 256, 0, stream>>>(flat, amask, W1, a_src1, a_dst1, W2, P1, P2,
                                   h1, s1, t1, W2T, P1T, P2T, out);
    // layer 1 (Dd=64, HD=192, PACK=4)
    krank<<<dim3(19, 3, 8), 256, 0, stream>>>(t1, partial);
    kscan<<<3, 256, 0, stream>>>(t1, s1, partial, inv, e1s, e2s, DenS1, DenP2, rks1);
    phA<64, 192, 4><<<dim3(60, 3), 256, 0, stream>>>(h1, inv, e1s, e2s, Tot1, Tot2);
    phB<64><<<2, 256, 0, stream>>>(Tot1, Tot2, Off1, Off2);
    phC<64, 192, 4><<<dim3(60, 3), 256, 0, stream>>>(h1, inv, e1s, e2s, Off1, Off2, Suf1, Pre2);
    kout1<<<300, 256, 0, stream>>>(s1, rks1, Suf1, Pre2, DenS1, DenP2, h1abf, s2, t2);
    gemm1<<<dim3(75, 6), 256, 0, stream>>>(h1abf, W2T, a_src2, a_dst2, h2, s2, t2);
    // layer 2 (Dd=128, HD=384, PACK=2)
    krank<<<dim3(19, 3, 8), 256, 0, stream>>>(t2, partial);
    kscan<<<3, 256, 0, stream>>>(t2, s2, partial, inv, e1s, e2s, DenS1, DenP2, rks2);
    phA<128, 384, 2><<<dim3(120, 3), 256, 0, stream>>>(h2, inv, e1s, e2s, Tot1, Tot2);
    phB<128><<<3, 256, 0, stream>>>(Tot1, Tot2, Off1, Off2);
    phC<128, 384, 2><<<dim3(120, 3), 256, 0, stream>>>(h2, inv, e1s, e2s, Off1, Off2, Suf1, Pre2);
    tail2<<<150, 256, 0, stream>>>(s2, rks2, Suf1, Pre2, DenS1, DenP2, flat, P1T, P2T, b1, b2, out);
}

// Round 8
// 254.970 us; speedup vs baseline: 6.3464x; 1.2179x over previous
//
#include <hip/hip_runtime.h>
#include <hip/hip_bf16.h>

typedef __attribute__((ext_vector_type(8))) short short8;
typedef __attribute__((ext_vector_type(4))) float f32x4;

#define NN 4800
#define NN1 4801
#define NC 240
#define CL 20
#define KLEN 600

__device__ __forceinline__ short bf16rne(float x) {
    unsigned u = __float_as_uint(x);
    u = (u + 0x7FFFu + ((u >> 16) & 1u)) >> 16;
    return (short)u;
}
// monotonic float->uint key (ascending float == ascending uint)
__device__ __forceinline__ unsigned fkey(float f) {
    unsigned i = __float_as_uint(f);
    return (i & 0x80000000u) ? ~i : (i | 0x80000000u);
}

// ---------- prep: h1, weight transposes, s1/t1 dots, mask copy, out zero ----------
__global__ __launch_bounds__(256) void prep(
    const float* __restrict__ flat, const float* __restrict__ amask,
    const float* __restrict__ W1, const float* __restrict__ as1, const float* __restrict__ ad1,
    const float* __restrict__ W2, const float* __restrict__ P1, const float* __restrict__ P2,
    float* __restrict__ h1, float* __restrict__ s1, float* __restrict__ t1,
    short* __restrict__ W2T, short* __restrict__ P1T, short* __restrict__ P2T,
    float* __restrict__ out) {
    const int gtid = blockIdx.x * 256 + threadIdx.x;
    const int GT = 1200 * 256;
    for (int x = gtid; x < 1030880; x += GT) {
        if (x < 921600) {
            int i = x / 192, c = x % 192;
            const float* fr = flat + i * 15;
            float acc = 0.f;
#pragma unroll
            for (int f = 0; f < 15; ++f) acc += fr[f] * W1[f * 192 + c];
            h1[x] = acc;
        } else if (x < 995328) {
            int y = x - 921600; int n = y / 192, k = y % 192;
            W2T[y] = bf16rne(W2[k * 384 + n]);
        } else if (x < 1015808) {
            int z = x - 995328; int n = z / 160, k = z % 160;
            P1T[z] = bf16rne(k < 143 ? P1[k * 128 + n] : 0.f);
        } else if (x < 1024000) {
            int z = x - 1015808; int n = z / 128, k = z % 128;
            P2T[z] = bf16rne(P2[k * 64 + n]);
        } else if (x < 1028832) {
            int m = x - 1024000;              // mask passthrough (4832)
            out[2048 + m] = amask[m];
        } else {
            out[x - 1028832] = 0.f;           // pool accumulators
        }
    }
    const int lane = threadIdx.x & 63;
    const int gw = (gtid >> 6);
    for (int task = gw; task < 3 * NN; task += (GT >> 6)) {
        int h = task / NN, i = task % NN;
        int col = h * 64 + lane;
        const float* fr = flat + i * 15;
        float hv = 0.f;
#pragma unroll
        for (int f = 0; f < 15; ++f) hv += fr[f] * W1[f * 192 + col];
        float ps = hv * as1[col], pt = hv * ad1[col];
#pragma unroll
        for (int off = 32; off; off >>= 1) { ps += __shfl_xor(ps, off); pt += __shfl_xor(pt, off); }
        if (lane == 0) { s1[h * NN + i] = ps; t1[h * NN + i] = pt; }
    }
}

// ---------- krank: partial rank counts, t-queries AND s-queries. grid (38,3,8) ----------
// q < NN : rank of t_q (strict order, global-index tiebreak)
// q >= NN: #{j : t_j <= -s_i}
__global__ __launch_bounds__(256) void krank(const float* __restrict__ s, const float* __restrict__ t,
                                             int* __restrict__ partial) {
    __shared__ __align__(16) unsigned ts[KLEN];
    const int h = blockIdx.y, kc = blockIdx.z;
    const float* tp = t + h * NN + kc * KLEN;
    for (int k = threadIdx.x; k < KLEN; k += 256) ts[k] = fkey(tp[k]);
    __syncthreads();
    int q = blockIdx.x * 256 + threadIdx.x;
    if (q >= 2 * NN) return;
    unsigned u; int tb;
    if (q < NN) { u = fkey(t[h * NN + q]); tb = q - kc * KLEN; }   // local-index tiebreak
    else        { u = fkey(-s[h * NN + q - NN]); tb = KLEN; }      // <= semantics
    int cnt = 0;
#pragma unroll 2
    for (int k = 0; k < KLEN; k += 4) {
        uint4 v = *(const uint4*)&ts[k];
        cnt += (v.x < u) || (v.x == u && (k + 0) < tb);
        cnt += (v.y < u) || (v.y == u && (k + 1) < tb);
        cnt += (v.z < u) || (v.z == u && (k + 2) < tb);
        cnt += (v.w < u) || (v.w == u && (k + 3) < tb);
    }
    partial[(kc * 3 + h) * (2 * NN) + q] = cnt;
}

// ---------- ksc1: sum partials -> scatter inv/e1s/e2s (t) or write rks (s). grid 113 ----------
__global__ __launch_bounds__(256) void ksc1(const float* __restrict__ t, const int* __restrict__ partial,
                                            int* __restrict__ inv, float* __restrict__ e1s,
                                            float* __restrict__ e2s, int* __restrict__ rks) {
    int idx = blockIdx.x * 256 + threadIdx.x;
    if (idx >= 3 * 2 * NN) return;
    int h = idx / (2 * NN), q = idx % (2 * NN);
    int sum = 0;
#pragma unroll
    for (int kc = 0; kc < 8; ++kc) sum += partial[(kc * 3 + h) * (2 * NN) + q];
    if (q < NN) {
        float tv = t[h * NN + q];
        inv[h * NN + sum] = q;
        e1s[h * NN + sum] = __expf(tv);
        e2s[h * NN + sum] = __expf(0.2f * tv);
    } else {
        rks[h * NN + q - NN] = sum;
    }
}

// ---------- phA: chunk totals. grid (NC/PACK, 3), PACK*Dd == 256 ----------
template <int Dd, int HD, int PACK>
__global__ __launch_bounds__(256) void phA(const float* __restrict__ hsrc, const int* __restrict__ inv,
                                           const float* __restrict__ e1s, const float* __restrict__ e2s,
                                           float* __restrict__ T1, float* __restrict__ T2) {
    __shared__ int inv_l[PACK * CL];
    __shared__ float w1s[PACK * CL], w2s[PACK * CL];
    const int h = blockIdx.y, tid = threadIdx.x;
    const int base = blockIdx.x * (PACK * CL);
    if (tid < PACK * CL) {
        inv_l[tid] = inv[h * NN + base + tid];
        w1s[tid] = e1s[h * NN + base + tid];
        w2s[tid] = e2s[h * NN + base + tid];
    }
    __syncthreads();
    const int sub = tid / Dd, d = tid % Dd;
    const int c = blockIdx.x * PACK + sub;
    float a1 = 0.f, a2 = 0.f;
#pragma unroll
    for (int p = 0; p < CL; ++p) {
        int j = inv_l[sub * CL + p];
        float hv = hsrc[(size_t)j * HD + h * Dd + d];
        a1 += w1s[sub * CL + p] * hv;
        a2 += w2s[sub * CL + p] * hv;
    }
    T1[(h * NC + c) * Dd + d] = a1;
    T2[(h * NC + c) * Dd + d] = a2;
}

// ---------- phBden: Tot scans (blocks < NB) + denominator scans (blocks NB..NB+2) ----------
template <int Dd, int NB>
__global__ __launch_bounds__(256) void phBden(const float* __restrict__ T1, const float* __restrict__ T2,
                                              const float* __restrict__ e1s, const float* __restrict__ e2s,
                                              float* __restrict__ O1, float* __restrict__ O2,
                                              float* __restrict__ DenS1, float* __restrict__ DenP2) {
    __shared__ float l1[NN], l2[NN];
    __shared__ float wsum[8];
    const int tid = threadIdx.x;
    if (blockIdx.x < NB) {
        int g = blockIdx.x * 256 + tid;
        if (g >= 2 * 3 * Dd) return;
        int dir = g / (3 * Dd), rest = g % (3 * Dd), h = rest / Dd, d = rest % Dd;
        if (dir == 0) {
            double r = 0; O1[(h * NC + NC - 1) * Dd + d] = 0.f;
#pragma unroll 8
            for (int c = NC - 2; c >= 0; --c) { r += (double)T1[(h * NC + c + 1) * Dd + d]; O1[(h * NC + c) * Dd + d] = (float)r; }
        } else {
            double r = 0; O2[h * NC * Dd + d] = 0.f;
#pragma unroll 8
            for (int c = 1; c < NC; ++c) { r += (double)T2[(h * NC + c - 1) * Dd + d]; O2[(h * NC + c) * Dd + d] = (float)r; }
        }
        return;
    }
    // denominator scan for head h (sorted e arrays, coalesced load)
    const int h = blockIdx.x - NB;
    for (int k = tid; k < NN; k += 256) { l1[k] = e1s[h * NN + k]; l2[k] = e2s[h * NN + k]; }
    __syncthreads();
    const int p0 = tid * 19;
    const int cnt = (p0 < NN) ? ((NN - p0 < 19) ? NN - p0 : 19) : 0;
    float sA = 0.f, sB = 0.f;
    for (int k = 0; k < cnt; ++k) { sA += l1[p0 + k]; sB += l2[p0 + k]; }
    float iA = sA, iB = sB;
    const int lane = tid & 63, w = tid >> 6;
#pragma unroll
    for (int d2 = 1; d2 < 64; d2 <<= 1) {
        float uA = __shfl_up(iA, d2), uB = __shfl_up(iB, d2);
        if (lane >= d2) { iA += uA; iB += uB; }
    }
    if (lane == 63) { wsum[w] = iA; wsum[4 + w] = iB; }
    __syncthreads();
    float baseA = 0.f, baseB = 0.f;
    for (int k = 0; k < w; ++k) { baseA += wsum[k]; baseB += wsum[4 + k]; }
    float TA = wsum[0] + wsum[1] + wsum[2] + wsum[3];
    float rA = baseA + iA - sA;    // exclusive prefix offsets
    float rB = baseB + iB - sB;
    for (int k = 0; k < cnt; ++k) {
        int p = p0 + k;
        DenS1[h * NN1 + p] = TA - rA;   // inclusive suffix of e1
        DenP2[h * NN1 + p] = rB;        // exclusive prefix of e2
        rA += l1[p]; rB += l2[p];
    }
    if (tid == 255) {
        DenS1[h * NN1 + NN] = 0.f;
        DenP2[h * NN1 + NN] = wsum[4] + wsum[5] + wsum[6] + wsum[7];
    }
}

// ---------- phC: emit Suf1 (incl suffix, e1) / Pre2 (excl prefix, e2) ----------
template <int Dd, int HD, int PACK>
__global__ __launch_bounds__(256) void phC(const float* __restrict__ hsrc, const int* __restrict__ inv,
                                           const float* __restrict__ e1s, const float* __restrict__ e2s,
                                           const float* __restrict__ O1, const float* __restrict__ O2,
                                           float* __restrict__ Suf1, float* __restrict__ Pre2) {
    __shared__ int inv_l[PACK * CL];
    __shared__ float w1s[PACK * CL], w2s[PACK * CL];
    const int h = blockIdx.y, tid = threadIdx.x;
    const int base = blockIdx.x * (PACK * CL);
    if (tid < PACK * CL) {
        inv_l[tid] = inv[h * NN + base + tid];
        w1s[tid] = e1s[h * NN + base + tid];
        w2s[tid] = e2s[h * NN + base + tid];
    }
    __syncthreads();
    const int sub = tid / Dd, d = tid % Dd;
    const int c = blockIdx.x * PACK + sub;
    float hv[CL];
#pragma unroll
    for (int p = 0; p < CL; ++p) {
        int j = inv_l[sub * CL + p];
        hv[p] = hsrc[(size_t)j * HD + h * Dd + d];
    }
    float r2 = O2[(h * NC + c) * Dd + d];
#pragma unroll
    for (int p = 0; p < CL; ++p) {
        int pp = c * CL + p;
        Pre2[((size_t)(h * NN1) + pp) * Dd + d] = r2;
        r2 += w2s[sub * CL + p] * hv[p];
    }
    if (c == NC - 1) {
        Pre2[((size_t)(h * NN1) + NN) * Dd + d] = r2;
        Suf1[((size_t)(h * NN1) + NN) * Dd + d] = 0.f;
    }
    float r1 = O1[(h * NC + c) * Dd + d];
#pragma unroll
    for (int p = CL - 1; p >= 0; --p) {
        int pp = c * CL + p;
        r1 += w1s[sub * CL + p] * hv[p];
        Suf1[((size_t)(h * NN1) + pp) * Dd + d] = r1;
    }
}

// ---------- kout1: combine + ELU -> h1abf; zero s2/t2. grid 300 ----------
__global__ __launch_bounds__(256) void kout1(const float* __restrict__ s1, const int* __restrict__ rks1,
                                             const float* __restrict__ Suf1, const float* __restrict__ Pre2,
                                             const float* __restrict__ DenS1, const float* __restrict__ DenP2,
                                             short* __restrict__ h1abf,
                                             float* __restrict__ s2, float* __restrict__ t2) {
    const int gtid = blockIdx.x * 256 + threadIdx.x;
    if (gtid < 3 * NN) { s2[gtid] = 0.f; t2[gtid] = 0.f; }
    for (int x = gtid; x < NN * 192; x += 300 * 256) {
        int i = x / 192, cc = x % 192, h = cc >> 6, d = cc & 63;
        float sv = s1[h * NN + i];
        float a = __expf(sv), b = __expf(0.2f * sv);
        int r = rks1[h * NN + i];
        size_t bp = ((size_t)(h * NN1) + r) * 64 + d;
        float num = a * Suf1[bp] + b * Pre2[bp];
        float den = a * DenS1[h * NN1 + r] + b * DenP2[h * NN1 + r];
        float v = num / den;
        v = v > 0.f ? v : (__expf(v) - 1.f);      // ELU
        h1abf[x] = bf16rne(v);
    }
}

// ---------- gemm1: h2 = h1a @ W2 + fused s2/t2 dots. grid (75,6) ----------
__global__ __launch_bounds__(256) void gemm1(const short* __restrict__ A, const short* __restrict__ W2T,
                                             const float* __restrict__ as2, const float* __restrict__ ad2,
                                             float* __restrict__ h2, float* __restrict__ s2,
                                             float* __restrict__ t2) {
    const int mb = blockIdx.x, nb = blockIdx.y, tid = threadIdx.x;
    const int lane = tid & 63, w = tid >> 6, q = lane >> 4, mr = lane & 15;
    const int m = mb * 64 + w * 16 + mr, n0 = nb * 64, hh = nb >> 1;
    f32x4 acc[4];
#pragma unroll
    for (int n = 0; n < 4; ++n) acc[n] = (f32x4){0.f, 0.f, 0.f, 0.f};
#pragma unroll
    for (int k0 = 0; k0 < 192; k0 += 32) {
        short8 af = *(const short8*)(A + (size_t)m * 192 + k0 + q * 8);
#pragma unroll
        for (int n = 0; n < 4; ++n) {
            short8 bf = *(const short8*)(W2T + (size_t)(n0 + n * 16 + mr) * 192 + k0 + q * 8);
            acc[n] = __builtin_amdgcn_mfma_f32_16x16x32_bf16(af, bf, acc[n], 0, 0, 0);
        }
    }
    float pse[4] = {0.f, 0.f, 0.f, 0.f}, pte[4] = {0.f, 0.f, 0.f, 0.f};
#pragma unroll
    for (int n = 0; n < 4; ++n) {
        int col = n0 + n * 16 + mr;
        float va = as2[col], vd = ad2[col];
#pragma unroll
        for (int r = 0; r < 4; ++r) {
            int row = mb * 64 + w * 16 + q * 4 + r;
            float v = acc[n][r];
            h2[(size_t)row * 384 + col] = v;
            pse[r] += v * va;
            pte[r] += v * vd;
        }
    }
#pragma unroll
    for (int off = 1; off < 16; off <<= 1) {
#pragma unroll
        for (int r = 0; r < 4; ++r) {
            pse[r] += __shfl_xor(pse[r], off);
            pte[r] += __shfl_xor(pte[r], off);
        }
    }
    if (mr == 0) {
#pragma unroll
        for (int r = 0; r < 4; ++r) {
            int row = mb * 64 + w * 16 + q * 4 + r;
            atomicAdd(&s2[hh * NN + row], pse[r]);
            atomicAdd(&t2[hh * NN + row], pte[r]);
        }
    }
}

// ---------- TAIL2: kout2 + F1 + F2 + mean pool. grid 150 (M=32) ----------
__global__ __launch_bounds__(256) void tail2(
    const float* __restrict__ s2, const int* __restrict__ rks2,
    const float* __restrict__ Suf1, const float* __restrict__ Pre2,
    const float* __restrict__ DenS1, const float* __restrict__ DenP2,
    const float* __restrict__ flat, const short* __restrict__ P1T, const short* __restrict__ P2T,
    const float* __restrict__ b1, const float* __restrict__ b2,
    float* __restrict__ out) {
    __shared__ short g[32][168];
    __shared__ short f1[32][136];
    const int mb = blockIdx.x, tid = threadIdx.x;
    for (int e = tid; e < 32 * 160; e += 256) {   // build g tile
        int row = e / 160, c = e % 160;
        int i = mb * 32 + row;
        float v;
        if (c < 128) {
            float acc = 0.f;
#pragma unroll
            for (int h = 0; h < 3; ++h) {
                float sv = s2[h * NN + i];
                float a = __expf(sv), b = __expf(0.2f * sv);
                int r = rks2[h * NN + i];
                size_t bp = ((size_t)(h * NN1) + r) * 128 + c;
                float num = a * Suf1[bp] + b * Pre2[bp];
                float den = a * DenS1[h * NN1 + r] + b * DenP2[h * NN1 + r];
                acc += num / den;
            }
            v = acc * (1.f / 3.f);
        } else if (c < 143) v = flat[i * 15 + (c - 128)];
        else v = 0.f;
        g[row][c] = bf16rne(v);
    }
    __syncthreads();
    const int lane = tid & 63, w = tid >> 6, q = lane >> 4, mr = lane & 15;
    const int s_ = w & 1;       // M-stripe (16 rows)
    const int ch = w >> 1;      // col-half
    f32x4 a1[4];
#pragma unroll
    for (int n = 0; n < 4; ++n) a1[n] = (f32x4){0.f, 0.f, 0.f, 0.f};
#pragma unroll
    for (int k0 = 0; k0 < 160; k0 += 32) {
        short8 af = *(const short8*)&g[s_ * 16 + mr][k0 + q * 8];
#pragma unroll
        for (int n = 0; n < 4; ++n) {
            short8 bf = *(const short8*)(P1T + (size_t)(ch * 64 + n * 16 + mr) * 160 + k0 + q * 8);
            a1[n] = __builtin_amdgcn_mfma_f32_16x16x32_bf16(af, bf, a1[n], 0, 0, 0);
        }
    }
#pragma unroll
    for (int n = 0; n < 4; ++n) {
        int col = ch * 64 + n * 16 + mr;
        float bv = b1[col];
#pragma unroll
        for (int r = 0; r < 4; ++r) {
            int row = s_ * 16 + q * 4 + r;
            f1[row][col] = bf16rne(fmaxf(a1[n][r] + bv, 0.f));
        }
    }
    __syncthreads();
    f32x4 a2[2];
#pragma unroll
    for (int n = 0; n < 2; ++n) a2[n] = (f32x4){0.f, 0.f, 0.f, 0.f};
#pragma unroll
    for (int k0 = 0; k0 < 128; k0 += 32) {
        short8 af = *(const short8*)&f1[s_ * 16 + mr][k0 + q * 8];
#pragma unroll
        for (int n = 0; n < 2; ++n) {
            short8 bf = *(const short8*)(P2T + (size_t)((ch * 2 + n) * 16 + mr) * 128 + k0 + q * 8);
            a2[n] = __builtin_amdgcn_mfma_f32_16x16x32_bf16(af, bf, a2[n], 0, 0, 0);
        }
    }
    float* f2f = (float*)&g[0][0];                 // reuse g LDS: 32*65*4 = 8.3 KB
#pragma unroll
    for (int n = 0; n < 2; ++n) {
        int col = (ch * 2 + n) * 16 + mr;
        float bv = b2[col];
#pragma unroll
        for (int r = 0; r < 4; ++r) {
            int row = s_ * 16 + q * 4 + r;
            f2f[row * 65 + col] = fmaxf(a2[n][r] + bv, 0.f);
        }
    }
    __syncthreads();
    if (tid < 64) {                                // mean pool (atomics into zeroed out)
        int d = tid;
        int b0 = (mb * 32) / 150;
        int bend = (mb * 32 + 31) / 150;
        float sa = 0.f, sb = 0.f;
        for (int row = 0; row < 32; ++row) {
            float v = f2f[row * 65 + d];
            int b = (mb * 32 + row) / 150;
            if (b == b0) sa += v; else sb += v;
        }
        atomicAdd(&out[b0 * 64 + d], sa * (1.f / 150.f));
        if (bend != b0) atomicAdd(&out[bend * 64 + d], sb * (1.f / 150.f));
    }
}

extern "C" void kernel_launch(void* const* d_in, const int* in_sizes, int n_in,
                              void* d_out, int out_size, void* d_ws, size_t ws_size,
                              hipStream_t stream) {
    const float* flat   = (const float*)d_in[0];
    const float* amask  = (const float*)d_in[1];
    const float* W1     = (const float*)d_in[2];
    const float* a_src1 = (const float*)d_in[3];
    const float* a_dst1 = (const float*)d_in[4];
    const float* W2     = (const float*)d_in[5];
    const float* a_src2 = (const float*)d_in[6];
    const float* a_dst2 = (const float*)d_in[7];
    const float* P1     = (const float*)d_in[8];
    const float* b1     = (const float*)d_in[9];
    const float* P2     = (const float*)d_in[10];
    const float* b2     = (const float*)d_in[11];
    float* out = (float*)d_out;

    char* wsb = (char*)d_ws;
    int*   partial = (int*)  (wsb + 0);         // 8*3*9600*4 = 921600
    float* s1      = (float*)(wsb + 921600);    // 57600
    float* t1      = (float*)(wsb + 979200);
    float* s2      = (float*)(wsb + 1036800);
    float* t2      = (float*)(wsb + 1094400);
    int*   rks1    = (int*)  (wsb + 1152000);   // 57600
    int*   rks2    = (int*)  (wsb + 1209600);
    float* h1      = (float*)(wsb + 1267200);   // 3686400
    int*   inv     = (int*)  (wsb + 4953600);   // 57600
    float* e1s     = (float*)(wsb + 5011200);
    float* e2s     = (float*)(wsb + 5068800);
    float* DenS1   = (float*)(wsb + 5126400);   // 57664
    float* DenP2   = (float*)(wsb + 5184064);   // 57664
    float* Tot1    = (float*)(wsb + 5241728);   // 368640
    float* Tot2    = (float*)(wsb + 5610368);
    float* Off1    = (float*)(wsb + 5979008);
    float* Off2    = (float*)(wsb + 6347648);
    float* Suf1    = (float*)(wsb + 6716288);   // 7374336
    float* Pre2    = (float*)(wsb + 14090624);  // 7374336
    float* h2      = (float*)(wsb + 21464960);  // 7372800
    short* h1abf   = (short*)(wsb + 28837760);  // 1843200
    short* W2T     = (short*)(wsb + 30680960);  // 147456
    short* P1T     = (short*)(wsb + 30828416);  // 40960
    short* P2T     = (short*)(wsb + 30869376);  // 16384 -> end 30885760

    prep<<<1200, 256, 0, stream>>>(flat, amask, W1, a_src1, a_dst1, W2, P1, P2,
                                   h1, s1, t1, W2T, P1T, P2T, out);
    // layer 1 (Dd=64, HD=192, PACK=4)
    krank<<<dim3(38, 3, 8), 256, 0, stream>>>(s1, t1, partial);
    ksc1<<<113, 256, 0, stream>>>(t1, partial, inv, e1s, e2s, rks1);
    phA<64, 192, 4><<<dim3(60, 3), 256, 0, stream>>>(h1, inv, e1s, e2s, Tot1, Tot2);
    phBden<64, 2><<<5, 256, 0, stream>>>(Tot1, Tot2, e1s, e2s, Off1, Off2, DenS1, DenP2);
    phC<64, 192, 4><<<dim3(60, 3), 256, 0, stream>>>(h1, inv, e1s, e2s, Off1, Off2, Suf1, Pre2);
    kout1<<<300, 256, 0, stream>>>(s1, rks1, Suf1, Pre2, DenS1, DenP2, h1abf, s2, t2);
    gemm1<<<dim3(75, 6), 256, 0, stream>>>(h1abf, W2T, a_src2, a_dst2, h2, s2, t2);
    // layer 2 (Dd=128, HD=384, PACK=2)
    krank<<<dim3(38, 3, 8), 256, 0, stream>>>(s2, t2, partial);
    ksc1<<<113, 256, 0, stream>>>(t2, partial, inv, e1s, e2s, rks2);
    phA<128, 384, 2><<<dim3(120, 3), 256, 0, stream>>>(h2, inv, e1s, e2s, Tot1, Tot2);
    phBden<128, 3><<<6, 256, 0, stream>>>(Tot1, Tot2, e1s, e2s, Off1, Off2, DenS1, DenP2);
    phC<128, 384, 2><<<dim3(120, 3), 256, 0, stream>>>(h2, inv, e1s, e2s, Off1, Off2, Suf1, Pre2);
    tail2<<<150, 256, 0, stream>>>(s2, rks2, Suf1, Pre2, DenS1, DenP2, flat, P1T, P2T, b1, b2, out);
}